// Round 1
// baseline (1505.513 us; speedup 1.0000x reference)
//
#include <hip/hip_runtime.h>
#include <hip/hip_bf16.h>
#include <math.h>

#define Dm 256
#define Hh 4
#define Nn 4096
#define Mq 4096
#define DH 64

// ---- workspace layout (bytes) ----
#define OFF_FLAG   0            // int: mask dtype flag
#define OFF_SMIN   64           // float: global score min
#define OFF_PART   1024         // 8192 floats: block partial mins (32KB)
#define OFF_TMAX   (64*1024)    // H*N*16 floats = 1MB
#define OFF_TSUM   (OFF_TMAX + (1<<20))
#define OFF_RMAX   (OFF_TSUM + (1<<20))     // H*N floats = 64KB
#define OFF_RINV   (OFF_RMAX + 64*1024)
#define OFF_Q      (4<<20)      // 256x4096 f32 = 4MB
#define OFF_K      (8<<20)      // 4MB
#define OFF_VT     (12<<20)     // v transposed [h][m][dd], 4MB
#define OFF_ATTN   (16<<20)     // 4MB
#define OFF_MSG    (20<<20)     // 4MB
#define OFF_H1     (24<<20)     // 512x4096 f32 = 8MB  -> total 32MB

// ---------------- mask dtype detection ----------------
// flag: 0=int32, 1=uint8/bool, 2=int64, 3=float32
__global__ void k_detect(const unsigned char* __restrict__ mb, int* __restrict__ flag) {
    __shared__ int c[5];
    if (threadIdx.x < 5) c[threadIdx.x] = 0;
    __syncthreads();
    for (int i = threadIdx.x; i < 16384; i += blockDim.x) {
        unsigned char b = mb[i];
        if (b) {
            atomicAdd(&c[i & 3], 1);
            if ((i & 7) == 4) atomicAdd(&c[4], 1);
        }
    }
    __syncthreads();
    if (threadIdx.x == 0) {
        int f;
        if (c[3] > 0 && c[0] == 0)          f = 3;  // float32: bytes 2,3 nonzero, byte0 zero
        else if (c[1] | c[2] | c[3])        f = 1;  // uint8/bool
        else if (c[4] > 0)                  f = 0;  // int32
        else                                f = 2;  // int64
        *flag = f;
    }
}

__device__ __forceinline__ float mask_madd(const void* mp, int flag, size_t idx, float smin) {
    int mv;
    if (flag == 1)      mv = ((const unsigned char*)mp)[idx];
    else if (flag == 0) mv = ((const int*)mp)[idx];
    else if (flag == 3) mv = (((const float*)mp)[idx] != 0.0f);
    else                mv = (int)(((const unsigned int*)mp)[2*idx] | ((const unsigned int*)mp)[2*idx+1]);
    return mv ? 0.0f : smin;
}

// ---------------- generic channel-major GEMM ----------------
// out[o,n] = act(bias[o] + sum_i W[o,i] * X[i,n]); X = concat(X0[0:split], X1[split:K])
// vtmode: write v transposed as vt[(h*M + n)*64 + dd] with o = dd*4+h
__global__ void k_gemm(const float* __restrict__ W, const float* __restrict__ bias,
                       const float* __restrict__ X0, const float* __restrict__ X1,
                       int K, int split, int N, float* __restrict__ out,
                       int relu, int vtmode) {
    int n  = blockIdx.x * 256 + threadIdx.x;
    int o0 = blockIdx.y * 4;
    float a0 = bias[o0], a1 = bias[o0+1], a2 = bias[o0+2], a3 = bias[o0+3];
    const float* w = W + (size_t)o0 * K;
    for (int i = 0; i < K; i++) {
        float xv = (i < split) ? X0[(size_t)i * N + n] : X1[(size_t)(i - split) * N + n];
        a0 = fmaf(w[i],           xv, a0);
        a1 = fmaf(w[(size_t)K+i], xv, a1);
        a2 = fmaf(w[2*(size_t)K+i], xv, a2);
        a3 = fmaf(w[3*(size_t)K+i], xv, a3);
    }
    if (relu) { a0 = fmaxf(a0,0.f); a1 = fmaxf(a1,0.f); a2 = fmaxf(a2,0.f); a3 = fmaxf(a3,0.f); }
    if (vtmode) {
        float av[4] = {a0,a1,a2,a3};
        #pragma unroll
        for (int oi = 0; oi < 4; oi++) {
            int o = o0 + oi, dd = o >> 2, h = o & 3;
            out[((size_t)h * Mq + n) * 64 + dd] = av[oi];
        }
    } else {
        out[(size_t)o0 * N + n]     = a0;
        out[((size_t)o0+1) * N + n] = a1;
        out[((size_t)o0+2) * N + n] = a2;
        out[((size_t)o0+3) * N + n] = a3;
    }
}

// ---------------- pass 1: global min of raw scores ----------------
// block: (m-tile 256, n-tile 32, head)
__global__ void k_minpass(const float* __restrict__ q, const float* __restrict__ kk,
                          float* __restrict__ partial) {
    const int h = blockIdx.z, n0 = blockIdx.y * 32, tid = threadIdx.x;
    const int m = blockIdx.x * 256 + tid;
    __shared__ float qs[64][32];
    for (int e = tid; e < 2048; e += 256) {
        int dd = e >> 5, j = e & 31;
        qs[dd][j] = q[(size_t)(dd*4 + h) * Nn + n0 + j];
    }
    __syncthreads();
    float s[32];
    #pragma unroll
    for (int j = 0; j < 32; j++) s[j] = 0.f;
    for (int dd = 0; dd < 64; dd++) {
        float kv = kk[(size_t)(dd*4 + h) * Mq + m];
        #pragma unroll
        for (int j = 0; j < 32; j++) s[j] = fmaf(kv, qs[dd][j], s[j]);
    }
    float mn = s[0];
    #pragma unroll
    for (int j = 1; j < 32; j++) mn = fminf(mn, s[j]);
    __shared__ float red[256];
    red[tid] = mn;
    __syncthreads();
    for (int st = 128; st > 0; st >>= 1) {
        if (tid < st) red[tid] = fminf(red[tid], red[tid + st]);
        __syncthreads();
    }
    if (tid == 0) {
        int bid = (blockIdx.z * 128 + blockIdx.y) * 16 + blockIdx.x;
        partial[bid] = red[0] * 0.125f;   // scale by 1/sqrt(64)
    }
}

__global__ void k_minreduce(const float* __restrict__ partial, float* __restrict__ smin) {
    const int tid = threadIdx.x;
    float mn = INFINITY;
    for (int i = tid; i < 8192; i += 256) mn = fminf(mn, partial[i]);
    __shared__ float red[256];
    red[tid] = mn;
    __syncthreads();
    for (int st = 128; st > 0; st >>= 1) {
        if (tid < st) red[tid] = fminf(red[tid], red[tid + st]);
        __syncthreads();
    }
    if (tid == 0) *smin = red[0];
}

// ---------------- pass 2: masked scores -> weights output + per-tile softmax stats ----------------
// block: (m-tile 256, n-tile 8), all 4 heads
__global__ void k_scores_stats(const float* __restrict__ q, const float* __restrict__ kk,
                               const void* __restrict__ mask,
                               const float* __restrict__ sminp, const int* __restrict__ flagp,
                               float* __restrict__ wout,
                               float* __restrict__ tmax, float* __restrict__ tsum) {
    const int mt = blockIdx.x, n0 = blockIdx.y * 8, tid = threadIdx.x;
    const int m = mt * 256 + tid;
    __shared__ float qs4[4][64][8];
    for (int e = tid; e < 2048; e += 256) {
        int h = e >> 9, dd = (e >> 3) & 63, j = e & 7;
        qs4[h][dd][j] = q[(size_t)(dd*4 + h) * Nn + n0 + j];
    }
    __syncthreads();
    float s[4][8];
    #pragma unroll
    for (int h = 0; h < 4; h++)
        #pragma unroll
        for (int j = 0; j < 8; j++) s[h][j] = 0.f;
    for (int dd = 0; dd < 64; dd++) {
        #pragma unroll
        for (int h = 0; h < 4; h++) {
            float kv = kk[(size_t)(dd*4 + h) * Mq + m];
            #pragma unroll
            for (int j = 0; j < 8; j++) s[h][j] = fmaf(kv, qs4[h][dd][j], s[h][j]);
        }
    }
    const float smin = *sminp;
    const int flag = *flagp;
    __shared__ float slds[32][257];
    #pragma unroll
    for (int j = 0; j < 8; j++) {
        float madd = mask_madd(mask, flag, (size_t)(n0 + j) * Mq + m, smin);
        float acc = 0.f;
        #pragma unroll
        for (int h = 0; h < 4; h++) {
            float v = s[h][j] * 0.125f + madd;
            s[h][j] = v;
            slds[h*8 + j][tid] = v;
            acc += v;
        }
        wout[(size_t)(n0 + j) * Mq + m] = 0.25f * acc;
    }
    __syncthreads();
    // 32 (h,row) pairs, 8 threads each reduce 256 columns
    const int p = tid >> 3, l = tid & 7;
    __shared__ float red[32][8];
    __shared__ float tmax_s[32];
    float mx = -INFINITY;
    for (int c = l; c < 256; c += 8) mx = fmaxf(mx, slds[p][c]);
    red[p][l] = mx;
    __syncthreads();
    if (l == 0) {
        float m2 = red[p][0];
        #pragma unroll
        for (int t = 1; t < 8; t++) m2 = fmaxf(m2, red[p][t]);
        tmax_s[p] = m2;
    }
    __syncthreads();
    float sm = 0.f;
    {
        float m2 = tmax_s[p];
        for (int c = l; c < 256; c += 8) sm += __expf(slds[p][c] - m2);
    }
    red[p][l] = sm;
    __syncthreads();
    if (l == 0) {
        float tot = red[p][0];
        #pragma unroll
        for (int t = 1; t < 8; t++) tot += red[p][t];
        int h = p >> 3, j = p & 7;
        size_t ridx = ((size_t)h * Nn + n0 + j) * 16 + mt;
        tmax[ridx] = tmax_s[p];
        tsum[ridx] = tot;
    }
}

// ---------------- pass 3: combine per-tile stats into row max / inv-sum ----------------
__global__ void k_combine(const float* __restrict__ tmax, const float* __restrict__ tsum,
                          float* __restrict__ rmax, float* __restrict__ rinv) {
    int r = blockIdx.x * 256 + threadIdx.x;   // h*N + n
    float mx = -INFINITY;
    #pragma unroll
    for (int t = 0; t < 16; t++) mx = fmaxf(mx, tmax[(size_t)r*16 + t]);
    float sm = 0.f;
    #pragma unroll
    for (int t = 0; t < 16; t++) sm += tsum[(size_t)r*16 + t] * __expf(tmax[(size_t)r*16 + t] - mx);
    rmax[r] = mx;
    rinv[r] = 1.0f / sm;
}

// ---------------- pass 4: recompute probs, PV accumulate ----------------
// block: (n-tile 32, head)
__global__ void k_pv(const float* __restrict__ q, const float* __restrict__ kk,
                     const float* __restrict__ vt, const void* __restrict__ mask,
                     const float* __restrict__ sminp, const int* __restrict__ flagp,
                     const float* __restrict__ rmax, const float* __restrict__ rinv,
                     float* __restrict__ attn) {
    const int h = blockIdx.y, n0 = blockIdx.x * 32, tid = threadIdx.x;
    __shared__ float qs[64][32];
    __shared__ float plds[256][36];
    __shared__ float rm[32], ri[32];
    for (int e = tid; e < 2048; e += 256) {
        int dd = e >> 5, j = e & 31;
        qs[dd][j] = q[(size_t)(dd*4 + h) * Nn + n0 + j];
    }
    if (tid < 32) {
        rm[tid] = rmax[(size_t)h * Nn + n0 + tid];
        ri[tid] = rinv[(size_t)h * Nn + n0 + tid];
    }
    __syncthreads();
    const float smin = *sminp;
    const int flag = *flagp;
    float acc[8];
    #pragma unroll
    for (int j = 0; j < 8; j++) acc[j] = 0.f;
    const int dd = tid & 63, g = tid >> 6;
    for (int mt = 0; mt < 16; mt++) {
        const int m = mt * 256 + tid;
        float s[32];
        #pragma unroll
        for (int j = 0; j < 32; j++) s[j] = 0.f;
        for (int d2 = 0; d2 < 64; d2++) {
            float kv = kk[(size_t)(d2*4 + h) * Mq + m];
            #pragma unroll
            for (int j = 0; j < 32; j++) s[j] = fmaf(kv, qs[d2][j], s[j]);
        }
        #pragma unroll
        for (int j = 0; j < 32; j++) {
            float madd = mask_madd(mask, flag, (size_t)(n0 + j) * Mq + m, smin);
            plds[tid][j] = __expf(s[j] * 0.125f + madd - rm[j]) * ri[j];
        }
        __syncthreads();
        const float* vb = vt + ((size_t)h * Mq + mt * 256) * 64;
        for (int mm = 0; mm < 256; mm++) {
            float vv = vb[(size_t)mm * 64 + dd];
            #pragma unroll
            for (int jj = 0; jj < 8; jj++)
                acc[jj] = fmaf(plds[mm][g*8 + jj], vv, acc[jj]);
        }
        __syncthreads();
    }
    #pragma unroll
    for (int jj = 0; jj < 8; jj++)
        attn[(size_t)(dd*4 + h) * Nn + n0 + g*8 + jj] = acc[jj];
}

extern "C" void kernel_launch(void* const* d_in, const int* in_sizes, int n_in,
                              void* d_out, int out_size, void* d_ws, size_t ws_size,
                              hipStream_t stream) {
    const float* x      = (const float*)d_in[0];
    const float* source = (const float*)d_in[1];
    // d_in[2] = dist (unused by reference)
    const void*  mask   = d_in[3];
    const float* Wq = (const float*)d_in[4];  const float* bq = (const float*)d_in[5];
    const float* Wk = (const float*)d_in[6];  const float* bk = (const float*)d_in[7];
    const float* Wv = (const float*)d_in[8];  const float* bv = (const float*)d_in[9];
    const float* Wm = (const float*)d_in[10]; const float* bm = (const float*)d_in[11];
    const float* W1 = (const float*)d_in[12]; const float* b1 = (const float*)d_in[13];
    const float* W2 = (const float*)d_in[14]; const float* b2 = (const float*)d_in[15];

    float* y    = (float*)d_out;                       // [256,4096]
    float* wout = y + (size_t)Dm * Nn;                 // [4096,4096]

    char* ws = (char*)d_ws;
    int*   flag  = (int*)(ws + OFF_FLAG);
    float* sminp = (float*)(ws + OFF_SMIN);
    float* part  = (float*)(ws + OFF_PART);
    float* tmax  = (float*)(ws + OFF_TMAX);
    float* tsum  = (float*)(ws + OFF_TSUM);
    float* rmax  = (float*)(ws + OFF_RMAX);
    float* rinv  = (float*)(ws + OFF_RINV);
    float* qb    = (float*)(ws + OFF_Q);
    float* kb    = (float*)(ws + OFF_K);
    float* vt    = (float*)(ws + OFF_VT);
    float* attn  = (float*)(ws + OFF_ATTN);
    float* msg   = (float*)(ws + OFF_MSG);
    float* h1    = (float*)(ws + OFF_H1);

    k_detect<<<1, 256, 0, stream>>>((const unsigned char*)mask, flag);

    k_gemm<<<dim3(16, 64), 256, 0, stream>>>(Wq, bq, x,      nullptr, 256, 256, Nn, qb, 0, 0);
    k_gemm<<<dim3(16, 64), 256, 0, stream>>>(Wk, bk, source, nullptr, 256, 256, Mq, kb, 0, 0);
    k_gemm<<<dim3(16, 64), 256, 0, stream>>>(Wv, bv, source, nullptr, 256, 256, Mq, vt, 0, 1);

    k_minpass<<<dim3(16, 128, 4), 256, 0, stream>>>(qb, kb, part);
    k_minreduce<<<1, 256, 0, stream>>>(part, sminp);

    k_scores_stats<<<dim3(16, 512), 256, 0, stream>>>(qb, kb, mask, sminp, flag, wout, tmax, tsum);
    k_combine<<<64, 256, 0, stream>>>(tmax, tsum, rmax, rinv);

    k_pv<<<dim3(128, 4), 256, 0, stream>>>(qb, kb, vt, mask, sminp, flag, rmax, rinv, attn);

    k_gemm<<<dim3(16, 64),  256, 0, stream>>>(Wm, bm, attn, nullptr, 256, 256, Nn, msg, 0, 0);
    k_gemm<<<dim3(16, 128), 256, 0, stream>>>(W1, b1, x,    msg,     512, 256, Nn, h1,  1, 0);
    k_gemm<<<dim3(16, 64),  256, 0, stream>>>(W2, b2, h1,   nullptr, 512, 512, Nn, y,   0, 0);
}

// Round 2
// 707.065 us; speedup vs baseline: 2.1292x; 2.1292x over previous
//
#include <hip/hip_runtime.h>
#include <hip/hip_bf16.h>
#include <math.h>

#define Dm 256
#define Hh 4
#define Nn 4096
#define Mq 4096

typedef __attribute__((ext_vector_type(8))) short bf16x8;
typedef __attribute__((ext_vector_type(4))) float f32x4;

#define MFMA_BF16(a,b,c) __builtin_amdgcn_mfma_f32_16x16x32_bf16(a,b,c,0,0,0)

// ---- workspace layout (bytes) ----
#define OFF_FLAG  0
#define OFF_SMIN  64
#define OFF_PART  1024                         // 512 f32 block-min partials
#define OFF_MT    (1u<<20)                     // 16384 f32 row maxes (64KB)
#define OFF_DENP  ((1u<<20) + (128u<<10))      // 16384*4 f32 denom partials (256KB)
#define OFF_STATS ((1u<<20) + (512u<<10))      // 16384*4*2 f32 class maxes (512KB) -> ends at 2MB
#define OFF_BITS  (2u<<20)                     // 2MB bitmask
#define OFF_QB    (4u<<20)                     // bf16 [h][n][dd] 2MB
#define OFF_KB    (6u<<20)                     // bf16 [h][m][dd] 2MB
#define OFF_VB    (8u<<20)                     // bf16 [h][dd][m] 2MB
#define OFF_ATTN  (10u<<20)                    // f32 [c][n] 4MB
#define OFF_MSG   (14u<<20)                    // f32 4MB
#define OFF_H1    (18u<<20)                    // f32 8MB -> total 26MB

__device__ __forceinline__ unsigned short f2bf(float x) {
    unsigned u = __float_as_uint(x);
    u += 0x7FFF + ((u >> 16) & 1);
    return (unsigned short)(u >> 16);
}

// ---------------- mask dtype detection ----------------
// flag: 0=int32, 1=uint8/bool, 2=int64, 3=float32
__global__ void k_detect(const unsigned char* __restrict__ mb, int* __restrict__ flag) {
    __shared__ int c[5];
    if (threadIdx.x < 5) c[threadIdx.x] = 0;
    __syncthreads();
    for (int i = threadIdx.x; i < 16384; i += blockDim.x) {
        unsigned char b = mb[i];
        if (b) {
            atomicAdd(&c[i & 3], 1);
            if ((i & 7) == 4) atomicAdd(&c[4], 1);
        }
    }
    __syncthreads();
    if (threadIdx.x == 0) {
        int f;
        if (c[3] > 0 && c[0] == 0)          f = 3;
        else if (c[1] | c[2] | c[3])        f = 1;
        else if (c[4] > 0)                  f = 0;
        else                                f = 2;
        *flag = f;
    }
}

// ---------------- mask -> bitmask (2MB) ----------------
__global__ void k_maskbits(const void* __restrict__ mp, const int* __restrict__ flagp,
                           unsigned char* __restrict__ bits) {
    size_t i = (size_t)blockIdx.x * 256 + threadIdx.x;   // byte index, 2M total
    const int flag = *flagp;
    size_t base = i * 8;
    unsigned b = 0;
    if (flag == 1) {
        unsigned long long u = *(const unsigned long long*)((const unsigned char*)mp + base);
        #pragma unroll
        for (int j = 0; j < 8; j++) b |= (unsigned)(((u >> (8*j)) & 0xFFull) != 0ull) << j;
    } else if (flag == 0) {
        const int* p = (const int*)mp;
        #pragma unroll
        for (int j = 0; j < 8; j++) b |= (unsigned)(p[base + j] != 0) << j;
    } else if (flag == 3) {
        const float* p = (const float*)mp;
        #pragma unroll
        for (int j = 0; j < 8; j++) b |= (unsigned)(p[base + j] != 0.0f) << j;
    } else {
        const unsigned long long* p = (const unsigned long long*)mp;
        #pragma unroll
        for (int j = 0; j < 8; j++) b |= (unsigned)(p[base + j] != 0ull) << j;
    }
    bits[i] = (unsigned char)b;
}

// ---------------- channel-major f32 GEMM with layout epilogues ----------------
// mode 0: f32 [o][n]; 1: f32 relu; 2: bf16 qk-layout [h][n][dd]; 3: bf16 v-layout [h][dd][m]
__global__ __launch_bounds__(256) void k_gemm(const float* __restrict__ W, const float* __restrict__ bias,
                       const float* __restrict__ X0, const float* __restrict__ X1,
                       int K, int split, void* __restrict__ out, int mode) {
    int n  = blockIdx.x * 256 + threadIdx.x;
    int o0 = blockIdx.y * 4;
    float a0 = bias[o0], a1 = bias[o0+1], a2 = bias[o0+2], a3 = bias[o0+3];
    const float* w = W + (size_t)o0 * K;
    for (int i = 0; i < K; i++) {
        float xv = (i < split) ? X0[(size_t)i * Nn + n] : X1[(size_t)(i - split) * Nn + n];
        a0 = fmaf(w[i],             xv, a0);
        a1 = fmaf(w[(size_t)K + i], xv, a1);
        a2 = fmaf(w[2*(size_t)K + i], xv, a2);
        a3 = fmaf(w[3*(size_t)K + i], xv, a3);
    }
    float av[4] = {a0, a1, a2, a3};
    if (mode <= 1) {
        float* o = (float*)out;
        #pragma unroll
        for (int oi = 0; oi < 4; oi++) {
            float v = (mode == 1) ? fmaxf(av[oi], 0.f) : av[oi];
            o[(size_t)(o0 + oi) * Nn + n] = v;
        }
    } else if (mode == 2) {
        short* o = (short*)out;
        #pragma unroll
        for (int oi = 0; oi < 4; oi++) {
            int c = o0 + oi;
            o[((size_t)(c & 3) * Nn + n) * 64 + (c >> 2)] = (short)f2bf(av[oi]);
        }
    } else {
        short* o = (short*)out;
        #pragma unroll
        for (int oi = 0; oi < 4; oi++) {
            int c = o0 + oi;
            o[((size_t)(c & 3) * 64 + (c >> 2)) * Nn + n] = (short)f2bf(av[oi]);
        }
    }
}

// ---------------- pass1: MFMA S^T, per-row class maxes + global min ----------------
__global__ __launch_bounds__(256) void k_pass1(
    const short* __restrict__ qb, const short* __restrict__ kb,
    const unsigned long long* __restrict__ bits,
    float* __restrict__ stats, float* __restrict__ partial) {
    const int tid = threadIdx.x;
    const int wv = tid >> 6, lane = tid & 63;
    const int h = wv;
    const int lg = lane >> 4, lr = lane & 15;
    const int n0 = blockIdx.x * 32;
    const int m0 = blockIdx.y * 1024;

    bf16x8 qf[2][2];
    #pragma unroll
    for (int ns = 0; ns < 2; ns++)
        #pragma unroll
        for (int ks = 0; ks < 2; ks++)
            qf[ns][ks] = *(const bf16x8*)(qb + (((size_t)h * Nn + n0 + ns*16 + lr) << 6) + ks*32 + lg*8);

    const unsigned long long* brow0 = bits + (((size_t)(n0 + lr)) << 6) + (m0 >> 6);
    const unsigned long long* brow1 = bits + (((size_t)(n0 + 16 + lr)) << 6) + (m0 >> 6);

    float mn = INFINITY;
    float mx1[2] = {-INFINITY, -INFINITY};
    float mx0[2] = {-INFINITY, -INFINITY};
    unsigned long long bw[2] = {0ull, 0ull};

    for (int ms = 0; ms < 64; ms++) {
        const size_t krow = ((size_t)h * Mq + m0 + ms*16 + lr) << 6;
        bf16x8 a0 = *(const bf16x8*)(kb + krow + lg*8);
        bf16x8 a1 = *(const bf16x8*)(kb + krow + 32 + lg*8);
        if ((ms & 3) == 0) { bw[0] = brow0[ms >> 2]; bw[1] = brow1[ms >> 2]; }
        const int shbase = (ms & 3) * 16 + lg * 4;
        #pragma unroll
        for (int ns = 0; ns < 2; ns++) {
            f32x4 acc = {0.f, 0.f, 0.f, 0.f};
            acc = MFMA_BF16(a0, qf[ns][0], acc);
            acc = MFMA_BF16(a1, qf[ns][1], acc);
            #pragma unroll
            for (int r = 0; r < 4; r++) {
                float v = acc[r] * 0.125f;
                mn = fminf(mn, v);
                bool b = (bw[ns] >> (shbase + r)) & 1ull;
                mx1[ns] = fmaxf(mx1[ns], b ? v : -INFINITY);
                mx0[ns] = fmaxf(mx0[ns], b ? -INFINITY : v);
            }
        }
    }
    #pragma unroll
    for (int ns = 0; ns < 2; ns++) {
        mx1[ns] = fmaxf(mx1[ns], __shfl_xor(mx1[ns], 16));
        mx1[ns] = fmaxf(mx1[ns], __shfl_xor(mx1[ns], 32));
        mx0[ns] = fmaxf(mx0[ns], __shfl_xor(mx0[ns], 16));
        mx0[ns] = fmaxf(mx0[ns], __shfl_xor(mx0[ns], 32));
    }
    if (lane < 16) {
        #pragma unroll
        for (int ns = 0; ns < 2; ns++) {
            size_t row = (size_t)h * Nn + n0 + ns*16 + lane;
            stats[(row*4 + blockIdx.y)*2 + 0] = mx1[ns];
            stats[(row*4 + blockIdx.y)*2 + 1] = mx0[ns];
        }
    }
    for (int off = 1; off < 64; off <<= 1) mn = fminf(mn, __shfl_xor(mn, off));
    __shared__ float wmin[4];
    if (lane == 0) wmin[wv] = mn;
    __syncthreads();
    if (tid == 0)
        partial[blockIdx.x*4 + blockIdx.y] = fminf(fminf(wmin[0], wmin[1]), fminf(wmin[2], wmin[3]));
}

__global__ void k_minreduce(const float* __restrict__ partial, float* __restrict__ smin) {
    const int tid = threadIdx.x;
    float mn = fminf(partial[tid], partial[tid + 256]);
    __shared__ float red[256];
    red[tid] = mn;
    __syncthreads();
    for (int st = 128; st > 0; st >>= 1) {
        if (tid < st) red[tid] = fminf(red[tid], red[tid + st]);
        __syncthreads();
    }
    if (tid == 0) *smin = red[0];
}

__global__ void k_rowfix(const float* __restrict__ stats, const float* __restrict__ sminp,
                         float* __restrict__ mtarr) {
    int row = blockIdx.x * 256 + threadIdx.x;   // 16384 rows
    float smin = *sminp;
    float mt = -INFINITY;
    #pragma unroll
    for (int mb = 0; mb < 4; mb++) {
        float a = stats[((size_t)row*4 + mb)*2];
        float b = stats[((size_t)row*4 + mb)*2 + 1];
        mt = fmaxf(mt, fmaxf(a, b + smin));
    }
    mtarr[row] = mt;
}

// ---------------- pass2: MFMA S^T -> weights + probs -> PV MFMA ----------------
__global__ __launch_bounds__(256) void k_pass2(
    const short* __restrict__ qb, const short* __restrict__ kb, const short* __restrict__ vb,
    const unsigned long long* __restrict__ bits,
    const float* __restrict__ sminp, const float* __restrict__ mtarr,
    float* __restrict__ wout, float* __restrict__ denp, float* __restrict__ attn) {
    __shared__ float swout[4][32][36];
    const int tid = threadIdx.x;
    const int wv = tid >> 6, lane = tid & 63;
    const int h = wv;
    const int lg = lane >> 4, lr = lane & 15;
    const int n0 = blockIdx.x * 32;
    const int m0 = blockIdx.y * 1024;
    const float smin = *sminp;

    bf16x8 qf[2][2];
    #pragma unroll
    for (int ns = 0; ns < 2; ns++)
        #pragma unroll
        for (int ks = 0; ks < 2; ks++)
            qf[ns][ks] = *(const bf16x8*)(qb + (((size_t)h * Nn + n0 + ns*16 + lr) << 6) + ks*32 + lg*8);

    float mt[2];
    mt[0] = mtarr[(size_t)h * Nn + n0 + lr];
    mt[1] = mtarr[(size_t)h * Nn + n0 + 16 + lr];

    const unsigned long long* brow0 = bits + (((size_t)(n0 + lr)) << 6) + (m0 >> 6);
    const unsigned long long* brow1 = bits + (((size_t)(n0 + 16 + lr)) << 6) + (m0 >> 6);

    f32x4 oacc[2][4];
    #pragma unroll
    for (int ns = 0; ns < 2; ns++)
        #pragma unroll
        for (int ds = 0; ds < 4; ds++)
            oacc[ns][ds] = (f32x4){0.f, 0.f, 0.f, 0.f};
    float dsum[2] = {0.f, 0.f};
    unsigned long long bw[2] = {0ull, 0ull};

    for (int cc = 0; cc < 32; cc++) {
        const int mch = m0 + cc * 32;
        if ((cc & 1) == 0) { bw[0] = brow0[cc >> 1]; bw[1] = brow1[cc >> 1]; }
        const int wsh = (cc & 1) * 32;
        #pragma unroll
        for (int msub = 0; msub < 2; msub++) {
            const size_t krow = ((size_t)h * Mq + mch + msub*16 + lr) << 6;
            bf16x8 a0 = *(const bf16x8*)(kb + krow + lg*8);
            bf16x8 a1 = *(const bf16x8*)(kb + krow + 32 + lg*8);
            const int shb = wsh + msub*16 + lg*4;
            #pragma unroll
            for (int ns = 0; ns < 2; ns++) {
                f32x4 acc = {0.f, 0.f, 0.f, 0.f};
                acc = MFMA_BF16(a0, qf[ns][0], acc);
                acc = MFMA_BF16(a1, qf[ns][1], acc);
                f32x4 msk;
                #pragma unroll
                for (int r = 0; r < 4; r++) {
                    bool b = (bw[ns] >> (shb + r)) & 1ull;
                    msk[r] = acc[r] * 0.125f + (b ? 0.f : smin);
                }
                *(f32x4*)&swout[h][ns*16 + lr][msub*16 + lg*4] = msk;
            }
        }
        __syncthreads();
        // final weights: mean over heads of masked scores
        #pragma unroll
        for (int r4 = 0; r4 < 4; r4++) {
            int idx = r4*256 + tid;
            int nl = idx >> 5, ml = idx & 31;
            float s = swout[0][nl][ml] + swout[1][nl][ml] + swout[2][nl][ml] + swout[3][nl][ml];
            wout[(size_t)(n0 + nl) * Mq + mch + ml] = 0.25f * s;
        }
        // V B-frags for this m-chunk
        bf16x8 vf[4];
        #pragma unroll
        for (int ds = 0; ds < 4; ds++)
            vf[ds] = *(const bf16x8*)(vb + ((size_t)(h*64 + ds*16 + lr)) * Mq + mch + lg*8);
        // P A-frags (exp on the fly) + PV MFMA
        #pragma unroll
        for (int ns = 0; ns < 2; ns++) {
            const float* srow = &swout[h][ns*16 + lr][lg*8];
            bf16x8 pf;
            #pragma unroll
            for (int i = 0; i < 8; i++) {
                float p = __expf(srow[i] - mt[ns]);
                dsum[ns] += p;
                pf[i] = (short)f2bf(p);
            }
            #pragma unroll
            for (int ds = 0; ds < 4; ds++)
                oacc[ns][ds] = MFMA_BF16(pf, vf[ds], oacc[ns][ds]);
        }
        __syncthreads();
    }
    // denom partials (deterministic, per m-block)
    #pragma unroll
    for (int ns = 0; ns < 2; ns++) {
        dsum[ns] += __shfl_xor(dsum[ns], 16);
        dsum[ns] += __shfl_xor(dsum[ns], 32);
    }
    if (lane < 16) {
        #pragma unroll
        for (int ns = 0; ns < 2; ns++)
            denp[((size_t)h * Nn + n0 + ns*16 + lane)*4 + blockIdx.y] = dsum[ns];
    }
    // unnormalized attn output [c][n], c = dd*4+h
    #pragma unroll
    for (int ns = 0; ns < 2; ns++)
        #pragma unroll
        for (int ds = 0; ds < 4; ds++)
            #pragma unroll
            for (int r = 0; r < 4; r++) {
                int dd = ds*16 + lr;
                int n = n0 + ns*16 + lg*4 + r;
                attn[(size_t)(dd*4 + h) * Nn + n] = oacc[ns][ds][r];
            }
}

__global__ void k_finish(float* __restrict__ attn, const float* __restrict__ denp) {
    size_t i = (size_t)blockIdx.x * 256 + threadIdx.x;   // 1M elements
    int c = (int)(i >> 12), n = (int)(i & 4095);
    size_t row = (size_t)(c & 3) * Nn + n;
    float d = denp[row*4] + denp[row*4 + 1] + denp[row*4 + 2] + denp[row*4 + 3];
    attn[i] = attn[i] / d;
}

extern "C" void kernel_launch(void* const* d_in, const int* in_sizes, int n_in,
                              void* d_out, int out_size, void* d_ws, size_t ws_size,
                              hipStream_t stream) {
    const float* x      = (const float*)d_in[0];
    const float* source = (const float*)d_in[1];
    const void*  mask   = d_in[3];
    const float* Wq = (const float*)d_in[4];  const float* bq = (const float*)d_in[5];
    const float* Wk = (const float*)d_in[6];  const float* bk = (const float*)d_in[7];
    const float* Wv = (const float*)d_in[8];  const float* bv = (const float*)d_in[9];
    const float* Wm = (const float*)d_in[10]; const float* bm = (const float*)d_in[11];
    const float* W1 = (const float*)d_in[12]; const float* b1 = (const float*)d_in[13];
    const float* W2 = (const float*)d_in[14]; const float* b2 = (const float*)d_in[15];

    float* y    = (float*)d_out;                // [256,4096]
    float* wout = y + (size_t)Dm * Nn;          // [4096,4096]

    char* ws = (char*)d_ws;
    int*   flag  = (int*)(ws + OFF_FLAG);
    float* sminp = (float*)(ws + OFF_SMIN);
    float* part  = (float*)(ws + OFF_PART);
    float* mtarr = (float*)(ws + OFF_MT);
    float* denp  = (float*)(ws + OFF_DENP);
    float* stats = (float*)(ws + OFF_STATS);
    unsigned char* bits = (unsigned char*)(ws + OFF_BITS);
    short* qb    = (short*)(ws + OFF_QB);
    short* kb    = (short*)(ws + OFF_KB);
    short* vb    = (short*)(ws + OFF_VB);
    float* attn  = (float*)(ws + OFF_ATTN);
    float* msg   = (float*)(ws + OFF_MSG);
    float* h1    = (float*)(ws + OFF_H1);

    k_detect<<<1, 256, 0, stream>>>((const unsigned char*)mask, flag);
    k_maskbits<<<8192, 256, 0, stream>>>(mask, flag, bits);

    k_gemm<<<dim3(16, 64), 256, 0, stream>>>(Wq, bq, x,      nullptr, 256, 256, qb, 2);
    k_gemm<<<dim3(16, 64), 256, 0, stream>>>(Wk, bk, source, nullptr, 256, 256, kb, 2);
    k_gemm<<<dim3(16, 64), 256, 0, stream>>>(Wv, bv, source, nullptr, 256, 256, vb, 3);

    k_pass1<<<dim3(128, 4), 256, 0, stream>>>(qb, kb, (const unsigned long long*)bits, stats, part);
    k_minreduce<<<1, 256, 0, stream>>>(part, sminp);
    k_rowfix<<<64, 256, 0, stream>>>(stats, sminp, mtarr);

    k_pass2<<<dim3(128, 4), 256, 0, stream>>>(qb, kb, vb, (const unsigned long long*)bits,
                                              sminp, mtarr, wout, denp, attn);
    k_finish<<<4096, 256, 0, stream>>>(attn, denp);

    k_gemm<<<dim3(16, 64),  256, 0, stream>>>(Wm, bm, attn, nullptr, 256, 256, msg, 0);
    k_gemm<<<dim3(16, 128), 256, 0, stream>>>(W1, b1, x,    msg,     512, 256, h1,  1);
    k_gemm<<<dim3(16, 64),  256, 0, stream>>>(W2, b2, h1,   nullptr, 512, 512, y,   0);
}

// Round 3
// 238.524 us; speedup vs baseline: 6.3118x; 2.9643x over previous
//
#include <hip/hip_runtime.h>
#include <hip/hip_bf16.h>
#include <math.h>

#define Dm 256
#define Hh 4
#define Nn 4096
#define Mq 4096

typedef __attribute__((ext_vector_type(8))) short bf16x8;
typedef __attribute__((ext_vector_type(4))) float f32x4;

#define MFMA_BF16(a,b,c) __builtin_amdgcn_mfma_f32_16x16x32_bf16(a,b,c,0,0,0)

#define MB (1u<<20)
// ---- workspace layout (bytes) ----
#define OFF_FLAG  0
#define OFF_SMIN  64
#define OFF_PART  1024                // 512 f32
#define OFF_MT    (64u<<10)           // 16384 f32
#define OFF_DENP  (128u<<10)          // 16384*4 f32
#define OFF_STATS (512u<<10)          // 16384*4*2 f32 -> ends 1MB
#define OFF_WB    (1u*MB)             // 655360 bf16 = 1.25MB -> ends 2.25MB
#define OFF_BITS  (5u*MB/2)           // 2MB bitmask -> ends 4.5MB
#define OFF_QB    (9u*MB/2)           // bf16 [h][n][64] 2MB
#define OFF_KB    (13u*MB/2)          // bf16 [h][m][64] 2MB
#define OFF_VB    (17u*MB/2)          // bf16 [h][64][m] 2MB
#define OFF_HCAT  (21u*MB/2)          // bf16 [n][512] 4MB
#define OFF_ATTNT (29u*MB/2)          // bf16 [n][256] 2MB
// union region at 16.5MB (xt/st die before opart; opart dies before h1t)
#define OFF_XT    (33u*MB/2)          // bf16 [n][256] 2MB
#define OFF_ST    (37u*MB/2)          // bf16 [n][256] 2MB
#define OFF_OPART (33u*MB/2)          // bf16 [4][c][n] 8MB -> ends 24.5MB
#define OFF_H1T   (33u*MB/2)          // bf16 [n][512] 4MB

// weight element offsets inside WB
#define WOFF_Q  0
#define WOFF_K  65536
#define WOFF_V  131072
#define WOFF_M  196608
#define WOFF_1  262144
#define WOFF_2  524288

__device__ __forceinline__ unsigned short f2bf(float x) {
    unsigned u = __float_as_uint(x);
    u += 0x7FFF + ((u >> 16) & 1);
    return (unsigned short)(u >> 16);
}
__device__ __forceinline__ float bf2f(unsigned short b) {
    return __uint_as_float(((unsigned)b) << 16);
}

// ---------------- mask dtype detection ----------------
__global__ void k_detect(const unsigned char* __restrict__ mb, int* __restrict__ flag) {
    __shared__ int c[5];
    if (threadIdx.x < 5) c[threadIdx.x] = 0;
    __syncthreads();
    for (int i = threadIdx.x; i < 16384; i += blockDim.x) {
        unsigned char b = mb[i];
        if (b) {
            atomicAdd(&c[i & 3], 1);
            if ((i & 7) == 4) atomicAdd(&c[4], 1);
        }
    }
    __syncthreads();
    if (threadIdx.x == 0) {
        int f;
        if (c[3] > 0 && c[0] == 0)          f = 3;
        else if (c[1] | c[2] | c[3])        f = 1;
        else if (c[4] > 0)                  f = 0;
        else                                f = 2;
        *flag = f;
    }
}

// ---------------- mask -> bitmask ----------------
__global__ void k_maskbits(const void* __restrict__ mp, const int* __restrict__ flagp,
                           unsigned char* __restrict__ bits) {
    size_t i = (size_t)blockIdx.x * 256 + threadIdx.x;
    const int flag = *flagp;
    size_t base = i * 8;
    unsigned b = 0;
    if (flag == 1) {
        unsigned long long u = *(const unsigned long long*)((const unsigned char*)mp + base);
        #pragma unroll
        for (int j = 0; j < 8; j++) b |= (unsigned)(((u >> (8*j)) & 0xFFull) != 0ull) << j;
    } else if (flag == 0) {
        const int* p = (const int*)mp;
        #pragma unroll
        for (int j = 0; j < 8; j++) b |= (unsigned)(p[base + j] != 0) << j;
    } else if (flag == 3) {
        const float* p = (const float*)mp;
        #pragma unroll
        for (int j = 0; j < 8; j++) b |= (unsigned)(p[base + j] != 0.0f) << j;
    } else {
        const unsigned long long* p = (const unsigned long long*)mp;
        #pragma unroll
        for (int j = 0; j < 8; j++) b |= (unsigned)(p[base + j] != 0ull) << j;
    }
    bits[i] = (unsigned char)b;
}

// ---------------- transpose-cast f32 [c][n] -> bf16 [n][c] (+optional hcat copy) ----------------
__global__ __launch_bounds__(256) void k_prep(const float* __restrict__ src,
                                              unsigned short* __restrict__ dst,
                                              unsigned short* __restrict__ dst2) {
    const int l = threadIdx.x & 63, g = threadIdx.x >> 6;
    const int c = blockIdx.y * 64 + l;
    const int n0 = blockIdx.x * 32 + g * 8;
    float4 v0 = *(const float4*)(src + (size_t)c * Nn + n0);
    float4 v1 = *(const float4*)(src + (size_t)c * Nn + n0 + 4);
    float vv[8] = {v0.x, v0.y, v0.z, v0.w, v1.x, v1.y, v1.z, v1.w};
    #pragma unroll
    for (int j = 0; j < 8; j++) {
        unsigned short b = f2bf(vv[j]);
        dst[(size_t)(n0 + j) * 256 + c] = b;
        if (dst2) dst2[(size_t)(n0 + j) * 512 + c] = b;
    }
}

// ---------------- cast all weights to bf16 ----------------
__global__ void k_wcast(const float* __restrict__ Wq, const float* __restrict__ Wk,
                        const float* __restrict__ Wv, const float* __restrict__ Wm,
                        const float* __restrict__ W1, const float* __restrict__ W2,
                        unsigned short* __restrict__ wb) {
    size_t i = (size_t)blockIdx.x * 256 + threadIdx.x;   // 655360 total
    const float* s; size_t off;
    if      (i < 131072 && i < 65536) { s = Wq; off = i; }
    else if (i < 131072)              { s = Wk; off = i - 65536; }
    else if (i < 196608)              { s = Wv; off = i - 131072; }
    else if (i < 262144)              { s = Wm; off = i - 196608; }
    else if (i < 524288)              { s = W1; off = i - 262144; }
    else                              { s = W2; off = i - 524288; }
    wb[i] = f2bf(s[off]);
}

// ---------------- MFMA GEMM: C[o][n] = bias[o] + sum_k W[o][k] Xt[n][k] ----------------
// MODE 0: f32 [o][n] (y). 1: bf16 qk-layout [h][n][dd]. 2: bf16 v-layout [h][dd][m].
// MODE 3: bf16 hcat[n][512] at c+256. 4: relu -> bf16 [n][512].
template<int KK, int MODE>
__global__ __launch_bounds__(256) void k_mgemm(const unsigned short* __restrict__ wb,
                                               const float* __restrict__ bias,
                                               const unsigned short* __restrict__ xt,
                                               void* __restrict__ out) {
    const int tid = threadIdx.x, w = tid >> 6, lane = tid & 63;
    const int lg = lane >> 4, lr = lane & 15;
    const int o_base = blockIdx.y * 64 + w * 16;
    const int n_base = blockIdx.x * 64;
    f32x4 acc[4];
    #pragma unroll
    for (int j = 0; j < 4; j++) acc[j] = (f32x4){0.f, 0.f, 0.f, 0.f};
    const unsigned short* wrow = wb + (size_t)(o_base + lr) * KK + lg * 8;
    const unsigned short* xrow = xt + (size_t)(n_base + lr) * KK + lg * 8;
    #pragma unroll
    for (int k0 = 0; k0 < KK; k0 += 32) {
        bf16x8 af = *(const bf16x8*)(wrow + k0);
        #pragma unroll
        for (int j = 0; j < 4; j++) {
            bf16x8 bfr = *(const bf16x8*)(xrow + (size_t)j * 16 * KK + k0);
            acc[j] = MFMA_BF16(af, bfr, acc[j]);
        }
    }
    float bv[4];
    #pragma unroll
    for (int r = 0; r < 4; r++) bv[r] = bias[o_base + lg * 4 + r];
    #pragma unroll
    for (int j = 0; j < 4; j++) {
        #pragma unroll
        for (int r = 0; r < 4; r++) {
            int o = o_base + lg * 4 + r;
            int n = n_base + j * 16 + lr;
            float v = acc[j][r] + bv[r];
            if (MODE == 0) {
                ((float*)out)[(size_t)o * Nn + n] = v;
            } else if (MODE == 1) {
                ((unsigned short*)out)[(((size_t)(o & 3)) * Nn + n) * 64 + (o >> 2)] = f2bf(v);
            } else if (MODE == 2) {
                ((unsigned short*)out)[(((size_t)(o & 3)) * 64 + (o >> 2)) * Nn + n] = f2bf(v);
            } else if (MODE == 3) {
                ((unsigned short*)out)[(size_t)n * 512 + 256 + o] = f2bf(v);
            } else {
                ((unsigned short*)out)[(size_t)n * 512 + o] = f2bf(fmaxf(v, 0.f));
            }
        }
    }
}

// ---------------- pass1: MFMA S^T, per-row class maxes + global min ----------------
__global__ __launch_bounds__(256) void k_pass1(
    const unsigned short* __restrict__ qb, const unsigned short* __restrict__ kb,
    const unsigned long long* __restrict__ bits,
    float* __restrict__ stats, float* __restrict__ partial) {
    const int tid = threadIdx.x;
    const int wv = tid >> 6, lane = tid & 63;
    const int h = wv;
    const int lg = lane >> 4, lr = lane & 15;
    const int n0 = blockIdx.x * 32;
    const int m0 = blockIdx.y * 1024;

    bf16x8 qf[2][2];
    #pragma unroll
    for (int ns = 0; ns < 2; ns++)
        #pragma unroll
        for (int ks = 0; ks < 2; ks++)
            qf[ns][ks] = *(const bf16x8*)(qb + (((size_t)h * Nn + n0 + ns*16 + lr) << 6) + ks*32 + lg*8);

    const unsigned long long* brow0 = bits + (((size_t)(n0 + lr)) << 6) + (m0 >> 6);
    const unsigned long long* brow1 = bits + (((size_t)(n0 + 16 + lr)) << 6) + (m0 >> 6);

    float mn = INFINITY;
    float mx1[2] = {-INFINITY, -INFINITY};
    float mx0[2] = {-INFINITY, -INFINITY};
    unsigned long long bw[2] = {0ull, 0ull};

    for (int ms = 0; ms < 64; ms++) {
        const size_t krow = ((size_t)h * Mq + m0 + ms*16 + lr) << 6;
        bf16x8 a0 = *(const bf16x8*)(kb + krow + lg*8);
        bf16x8 a1 = *(const bf16x8*)(kb + krow + 32 + lg*8);
        if ((ms & 3) == 0) { bw[0] = brow0[ms >> 2]; bw[1] = brow1[ms >> 2]; }
        const int shbase = (ms & 3) * 16 + lg * 4;
        #pragma unroll
        for (int ns = 0; ns < 2; ns++) {
            f32x4 acc = {0.f, 0.f, 0.f, 0.f};
            acc = MFMA_BF16(a0, qf[ns][0], acc);
            acc = MFMA_BF16(a1, qf[ns][1], acc);
            #pragma unroll
            for (int r = 0; r < 4; r++) {
                float v = acc[r] * 0.125f;
                mn = fminf(mn, v);
                bool b = (bw[ns] >> (shbase + r)) & 1ull;
                mx1[ns] = fmaxf(mx1[ns], b ? v : -INFINITY);
                mx0[ns] = fmaxf(mx0[ns], b ? -INFINITY : v);
            }
        }
    }
    #pragma unroll
    for (int ns = 0; ns < 2; ns++) {
        mx1[ns] = fmaxf(mx1[ns], __shfl_xor(mx1[ns], 16));
        mx1[ns] = fmaxf(mx1[ns], __shfl_xor(mx1[ns], 32));
        mx0[ns] = fmaxf(mx0[ns], __shfl_xor(mx0[ns], 16));
        mx0[ns] = fmaxf(mx0[ns], __shfl_xor(mx0[ns], 32));
    }
    if (lane < 16) {
        #pragma unroll
        for (int ns = 0; ns < 2; ns++) {
            size_t row = (size_t)h * Nn + n0 + ns*16 + lane;
            stats[(row*4 + blockIdx.y)*2 + 0] = mx1[ns];
            stats[(row*4 + blockIdx.y)*2 + 1] = mx0[ns];
        }
    }
    for (int off = 1; off < 64; off <<= 1) mn = fminf(mn, __shfl_xor(mn, off));
    __shared__ float wmin[4];
    if (lane == 0) wmin[wv] = mn;
    __syncthreads();
    if (tid == 0)
        partial[blockIdx.x*4 + blockIdx.y] = fminf(fminf(wmin[0], wmin[1]), fminf(wmin[2], wmin[3]));
}

__global__ void k_minreduce(const float* __restrict__ partial, float* __restrict__ smin) {
    const int tid = threadIdx.x;
    float mn = fminf(partial[tid], partial[tid + 256]);
    __shared__ float red[256];
    red[tid] = mn;
    __syncthreads();
    for (int st = 128; st > 0; st >>= 1) {
        if (tid < st) red[tid] = fminf(red[tid], red[tid + st]);
        __syncthreads();
    }
    if (tid == 0) *smin = red[0];
}

__global__ void k_rowfix(const float* __restrict__ stats, const float* __restrict__ sminp,
                         float* __restrict__ mtarr) {
    int row = blockIdx.x * 256 + threadIdx.x;
    float smin = *sminp;
    float mt = -INFINITY;
    #pragma unroll
    for (int mb = 0; mb < 4; mb++) {
        float a = stats[((size_t)row*4 + mb)*2];
        float b = stats[((size_t)row*4 + mb)*2 + 1];
        mt = fmaxf(mt, fmaxf(a, b + smin));
    }
    mtarr[row] = mt;
}

// ---------------- pass2: MFMA S^T -> weights + probs -> PV MFMA (partials per m-block) ----------------
__global__ __launch_bounds__(256) void k_pass2(
    const unsigned short* __restrict__ qb, const unsigned short* __restrict__ kb,
    const unsigned short* __restrict__ vb,
    const unsigned long long* __restrict__ bits,
    const float* __restrict__ sminp, const float* __restrict__ mtarr,
    float* __restrict__ wout, float* __restrict__ denp, unsigned short* __restrict__ opart) {
    __shared__ float swout[4][32][36];
    const int tid = threadIdx.x;
    const int wv = tid >> 6, lane = tid & 63;
    const int h = wv;
    const int lg = lane >> 4, lr = lane & 15;
    const int n0 = blockIdx.x * 32;
    const int m0 = blockIdx.y * 1024;
    const float smin = *sminp;

    bf16x8 qf[2][2];
    #pragma unroll
    for (int ns = 0; ns < 2; ns++)
        #pragma unroll
        for (int ks = 0; ks < 2; ks++)
            qf[ns][ks] = *(const bf16x8*)(qb + (((size_t)h * Nn + n0 + ns*16 + lr) << 6) + ks*32 + lg*8);

    float mt[2];
    mt[0] = mtarr[(size_t)h * Nn + n0 + lr];
    mt[1] = mtarr[(size_t)h * Nn + n0 + 16 + lr];

    const unsigned long long* brow0 = bits + (((size_t)(n0 + lr)) << 6) + (m0 >> 6);
    const unsigned long long* brow1 = bits + (((size_t)(n0 + 16 + lr)) << 6) + (m0 >> 6);

    f32x4 oacc[2][4];
    #pragma unroll
    for (int ns = 0; ns < 2; ns++)
        #pragma unroll
        for (int ds = 0; ds < 4; ds++)
            oacc[ns][ds] = (f32x4){0.f, 0.f, 0.f, 0.f};
    float dsum[2] = {0.f, 0.f};
    unsigned long long bw[2] = {0ull, 0ull};

    for (int cc = 0; cc < 32; cc++) {
        const int mch = m0 + cc * 32;
        if ((cc & 1) == 0) { bw[0] = brow0[cc >> 1]; bw[1] = brow1[cc >> 1]; }
        const int wsh = (cc & 1) * 32;
        #pragma unroll
        for (int msub = 0; msub < 2; msub++) {
            const size_t krow = ((size_t)h * Mq + mch + msub*16 + lr) << 6;
            bf16x8 a0 = *(const bf16x8*)(kb + krow + lg*8);
            bf16x8 a1 = *(const bf16x8*)(kb + krow + 32 + lg*8);
            const int shb = wsh + msub*16 + lg*4;
            #pragma unroll
            for (int ns = 0; ns < 2; ns++) {
                f32x4 acc = {0.f, 0.f, 0.f, 0.f};
                acc = MFMA_BF16(a0, qf[ns][0], acc);
                acc = MFMA_BF16(a1, qf[ns][1], acc);
                f32x4 msk;
                #pragma unroll
                for (int r = 0; r < 4; r++) {
                    bool b = (bw[ns] >> (shb + r)) & 1ull;
                    msk[r] = acc[r] * 0.125f + (b ? 0.f : smin);
                }
                *(f32x4*)&swout[h][ns*16 + lr][msub*16 + lg*4] = msk;
            }
        }
        __syncthreads();
        #pragma unroll
        for (int r4 = 0; r4 < 4; r4++) {
            int idx = r4*256 + tid;
            int nl = idx >> 5, ml = idx & 31;
            float s = swout[0][nl][ml] + swout[1][nl][ml] + swout[2][nl][ml] + swout[3][nl][ml];
            wout[(size_t)(n0 + nl) * Mq + mch + ml] = 0.25f * s;
        }
        bf16x8 vf[4];
        #pragma unroll
        for (int ds = 0; ds < 4; ds++)
            vf[ds] = *(const bf16x8*)(vb + ((size_t)(h*64 + ds*16 + lr)) * Mq + mch + lg*8);
        #pragma unroll
        for (int ns = 0; ns < 2; ns++) {
            const float* srow = &swout[h][ns*16 + lr][lg*8];
            bf16x8 pf;
            #pragma unroll
            for (int i = 0; i < 8; i++) {
                float p = __expf(srow[i] - mt[ns]);
                dsum[ns] += p;
                pf[i] = (short)f2bf(p);
            }
            #pragma unroll
            for (int ds = 0; ds < 4; ds++)
                oacc[ns][ds] = MFMA_BF16(pf, vf[ds], oacc[ns][ds]);
        }
        __syncthreads();
    }
    #pragma unroll
    for (int ns = 0; ns < 2; ns++) {
        dsum[ns] += __shfl_xor(dsum[ns], 16);
        dsum[ns] += __shfl_xor(dsum[ns], 32);
    }
    if (lane < 16) {
        #pragma unroll
        for (int ns = 0; ns < 2; ns++)
            denp[((size_t)h * Nn + n0 + ns*16 + lane)*4 + blockIdx.y] = dsum[ns];
    }
    unsigned short* op = opart + (size_t)blockIdx.y * (Dm * Nn);
    #pragma unroll
    for (int ns = 0; ns < 2; ns++)
        #pragma unroll
        for (int ds = 0; ds < 4; ds++)
            #pragma unroll
            for (int r = 0; r < 4; r++) {
                int dd = ds*16 + lr;
                int n = n0 + ns*16 + lg*4 + r;
                op[(size_t)(dd*4 + h) * Nn + n] = f2bf(oacc[ns][ds][r]);
            }
}

// ---------------- finish: sum partials, normalize, transpose -> attnT[n][c] bf16 ----------------
__global__ __launch_bounds__(256) void k_finish(const unsigned short* __restrict__ opart,
                                                const float* __restrict__ denp,
                                                unsigned short* __restrict__ attnT) {
    __shared__ float t[64][65];
    const int cb = blockIdx.y * 64, nb = blockIdx.x * 64;
    const int tid = threadIdx.x;
    #pragma unroll
    for (int e = 0; e < 16; e++) {
        int idx = e * 256 + tid;
        int c_l = idx >> 6, n_l = idx & 63;
        int c = cb + c_l, n = nb + n_l;
        float s = 0.f;
        #pragma unroll
        for (int y = 0; y < 4; y++)
            s += bf2f(opart[(size_t)y * (Dm*Nn) + (size_t)c * Nn + n]);
        size_t row = (size_t)(c & 3) * Nn + n;
        float d = denp[row*4] + denp[row*4+1] + denp[row*4+2] + denp[row*4+3];
        t[c_l][n_l] = s / d;
    }
    __syncthreads();
    #pragma unroll
    for (int e = 0; e < 16; e++) {
        int idx = e * 256 + tid;
        int n_l = idx >> 6, c_l = idx & 63;
        attnT[(size_t)(nb + n_l) * 256 + cb + c_l] = f2bf(t[c_l][n_l]);
    }
}

extern "C" void kernel_launch(void* const* d_in, const int* in_sizes, int n_in,
                              void* d_out, int out_size, void* d_ws, size_t ws_size,
                              hipStream_t stream) {
    const float* x      = (const float*)d_in[0];
    const float* source = (const float*)d_in[1];
    const void*  mask   = d_in[3];
    const float* Wq = (const float*)d_in[4];  const float* bq = (const float*)d_in[5];
    const float* Wk = (const float*)d_in[6];  const float* bk = (const float*)d_in[7];
    const float* Wv = (const float*)d_in[8];  const float* bv = (const float*)d_in[9];
    const float* Wm = (const float*)d_in[10]; const float* bm = (const float*)d_in[11];
    const float* W1 = (const float*)d_in[12]; const float* b1 = (const float*)d_in[13];
    const float* W2 = (const float*)d_in[14]; const float* b2 = (const float*)d_in[15];

    float* y    = (float*)d_out;                // [256,4096]
    float* wout = y + (size_t)Dm * Nn;          // [4096,4096]

    char* ws = (char*)d_ws;
    int*   flag  = (int*)(ws + OFF_FLAG);
    float* sminp = (float*)(ws + OFF_SMIN);
    float* part  = (float*)(ws + OFF_PART);
    float* mtarr = (float*)(ws + OFF_MT);
    float* denp  = (float*)(ws + OFF_DENP);
    float* stats = (float*)(ws + OFF_STATS);
    unsigned short* wb    = (unsigned short*)(ws + OFF_WB);
    unsigned char*  bits  = (unsigned char*)(ws + OFF_BITS);
    unsigned short* qb    = (unsigned short*)(ws + OFF_QB);
    unsigned short* kb    = (unsigned short*)(ws + OFF_KB);
    unsigned short* vb    = (unsigned short*)(ws + OFF_VB);
    unsigned short* hcat  = (unsigned short*)(ws + OFF_HCAT);
    unsigned short* attnT = (unsigned short*)(ws + OFF_ATTNT);
    unsigned short* xt    = (unsigned short*)(ws + OFF_XT);
    unsigned short* st    = (unsigned short*)(ws + OFF_ST);
    unsigned short* opart = (unsigned short*)(ws + OFF_OPART);
    unsigned short* h1t   = (unsigned short*)(ws + OFF_H1T);

    k_detect<<<1, 256, 0, stream>>>((const unsigned char*)mask, flag);
    k_maskbits<<<8192, 256, 0, stream>>>(mask, flag, bits);

    k_prep<<<dim3(128, 4), 256, 0, stream>>>(x, xt, hcat);
    k_prep<<<dim3(128, 4), 256, 0, stream>>>(source, st, nullptr);
    k_wcast<<<2560, 256, 0, stream>>>(Wq, Wk, Wv, Wm, W1, W2, wb);

    k_mgemm<256, 1><<<dim3(64, 4), 256, 0, stream>>>(wb + WOFF_Q, bq, xt, qb);
    k_mgemm<256, 1><<<dim3(64, 4), 256, 0, stream>>>(wb + WOFF_K, bk, st, kb);
    k_mgemm<256, 2><<<dim3(64, 4), 256, 0, stream>>>(wb + WOFF_V, bv, st, vb);

    k_pass1<<<dim3(128, 4), 256, 0, stream>>>(qb, kb, (const unsigned long long*)bits, stats, part);
    k_minreduce<<<1, 256, 0, stream>>>(part, sminp);
    k_rowfix<<<64, 256, 0, stream>>>(stats, sminp, mtarr);

    k_pass2<<<dim3(128, 4), 256, 0, stream>>>(qb, kb, vb, (const unsigned long long*)bits,
                                              sminp, mtarr, wout, denp, opart);
    k_finish<<<dim3(64, 4), 256, 0, stream>>>(opart, denp, attnT);

    k_mgemm<256, 3><<<dim3(64, 4), 256, 0, stream>>>(wb + WOFF_M, bm, attnT, hcat);
    k_mgemm<512, 4><<<dim3(64, 8), 256, 0, stream>>>(wb + WOFF_1, b1, hcat, h1t);
    k_mgemm<512, 0><<<dim3(64, 4), 256, 0, stream>>>(wb + WOFF_2, b2, h1t, y);
}

// Round 4
// 235.307 us; speedup vs baseline: 6.3981x; 1.0137x over previous
//
#include <hip/hip_runtime.h>
#include <hip/hip_bf16.h>
#include <math.h>

#define Dm 256
#define Hh 4
#define Nn 4096
#define Mq 4096

typedef __attribute__((ext_vector_type(8))) short bf16x8;
typedef __attribute__((ext_vector_type(4))) float f32x4;
typedef _Float16 __attribute__((ext_vector_type(4))) f16x4;

#define MFMA_BF16(a,b,c) __builtin_amdgcn_mfma_f32_16x16x32_bf16(a,b,c,0,0,0)
#define MFMA_F16x16(a,b,c) __builtin_amdgcn_mfma_f32_16x16x16f16(a,b,c,0,0,0)

#define MB (1u<<20)
// ---- workspace layout (bytes); ws >= 32MB proven in round 1 ----
#define OFF_FLAG  0
#define OFF_SMIN  64
#define OFF_PART  128                 // 256 f32
#define OFF_MT    4096                // 16384 f32 (64KB)
#define OFF_DENP  (128u<<10)          // 16384*4 f32 (256KB)
#define OFF_STATS (512u<<10)          // 16384*16 f32 (1MB) -> ends 1.5MB
#define OFF_WB    (3u*MB/2)           // 655360 bf16 (1.25MB) -> ends 2.75MB
#define OFF_BITS  (3u*MB)             // 2MB bitmask -> ends 5MB
#define OFF_QB    (5u*MB)             // bf16 [h][n][64] 2MB
#define OFF_KB    (7u*MB)             // bf16 [h][m][64] swizzled 2MB
#define OFF_VB    (9u*MB)             // fp16 [h][dd][m] 2MB
#define OFF_HCAT  (11u*MB)            // bf16 [n][512] 4MB
#define OFF_ATTNT (15u*MB)            // bf16 [n][256] 2MB
// overlap region (xt/st die after QKV; opart dies after finish)
#define OFF_XT    (17u*MB)            // bf16 [n][256] 2MB
#define OFF_ST    (19u*MB)            // bf16 [n][256] 2MB
#define OFF_OPART (17u*MB)            // bf16 [4][c][n] 8MB -> ends 25MB
#define OFF_H1T   (17u*MB)            // bf16 [n][512] 4MB

#define WOFF_Q  0
#define WOFF_K  65536
#define WOFF_V  131072
#define WOFF_M  196608
#define WOFF_1  262144
#define WOFF_2  524288

__device__ __forceinline__ unsigned short f2bf(float x) {
    unsigned u = __float_as_uint(x);
    u += 0x7FFF + ((u >> 16) & 1);
    return (unsigned short)(u >> 16);
}
__device__ __forceinline__ float bf2f(unsigned short b) {
    return __uint_as_float(((unsigned)b) << 16);
}

// ---------------- mask dtype detection ----------------
__global__ void k_detect(const unsigned char* __restrict__ mb, int* __restrict__ flag) {
    __shared__ int c[5];
    if (threadIdx.x < 5) c[threadIdx.x] = 0;
    __syncthreads();
    for (int i = threadIdx.x; i < 16384; i += blockDim.x) {
        unsigned char b = mb[i];
        if (b) {
            atomicAdd(&c[i & 3], 1);
            if ((i & 7) == 4) atomicAdd(&c[4], 1);
        }
    }
    __syncthreads();
    if (threadIdx.x == 0) {
        int f;
        if (c[3] > 0 && c[0] == 0)          f = 3;
        else if (c[1] | c[2] | c[3])        f = 1;
        else if (c[4] > 0)                  f = 0;
        else                                f = 2;
        *flag = f;
    }
}

// ---------------- mask -> bitmask ----------------
__global__ void k_maskbits(const void* __restrict__ mp, const int* __restrict__ flagp,
                           unsigned char* __restrict__ bits) {
    size_t i = (size_t)blockIdx.x * 256 + threadIdx.x;
    const int flag = *flagp;
    size_t base = i * 8;
    unsigned b = 0;
    if (flag == 1) {
        unsigned long long u = *(const unsigned long long*)((const unsigned char*)mp + base);
        #pragma unroll
        for (int j = 0; j < 8; j++) b |= (unsigned)(((u >> (8*j)) & 0xFFull) != 0ull) << j;
    } else if (flag == 0) {
        const int* p = (const int*)mp;
        #pragma unroll
        for (int j = 0; j < 8; j++) b |= (unsigned)(p[base + j] != 0) << j;
    } else if (flag == 3) {
        const float* p = (const float*)mp;
        #pragma unroll
        for (int j = 0; j < 8; j++) b |= (unsigned)(p[base + j] != 0.0f) << j;
    } else {
        const unsigned long long* p = (const unsigned long long*)mp;
        #pragma unroll
        for (int j = 0; j < 8; j++) b |= (unsigned)(p[base + j] != 0ull) << j;
    }
    bits[i] = (unsigned char)b;
}

// ---------------- transpose-cast f32 [c][n] -> bf16 [n][c] (+optional hcat copy) ----------------
__global__ __launch_bounds__(256) void k_prep(const float* __restrict__ src,
                                              unsigned short* __restrict__ dst,
                                              unsigned short* __restrict__ dst2) {
    const int l = threadIdx.x & 63, g = threadIdx.x >> 6;
    const int c = blockIdx.y * 64 + l;
    const int n0 = blockIdx.x * 32 + g * 8;
    float4 v0 = *(const float4*)(src + (size_t)c * Nn + n0);
    float4 v1 = *(const float4*)(src + (size_t)c * Nn + n0 + 4);
    float vv[8] = {v0.x, v0.y, v0.z, v0.w, v1.x, v1.y, v1.z, v1.w};
    #pragma unroll
    for (int j = 0; j < 8; j++) {
        unsigned short b = f2bf(vv[j]);
        dst[(size_t)(n0 + j) * 256 + c] = b;
        if (dst2) dst2[(size_t)(n0 + j) * 512 + c] = b;
    }
}

// ---------------- cast all weights to bf16 ----------------
__global__ void k_wcast(const float* __restrict__ Wq, const float* __restrict__ Wk,
                        const float* __restrict__ Wv, const float* __restrict__ Wm,
                        const float* __restrict__ W1, const float* __restrict__ W2,
                        unsigned short* __restrict__ wb) {
    size_t i = (size_t)blockIdx.x * 256 + threadIdx.x;
    const float* s; size_t off;
    if      (i < 65536)               { s = Wq; off = i; }
    else if (i < 131072)              { s = Wk; off = i - 65536; }
    else if (i < 196608)              { s = Wv; off = i - 131072; }
    else if (i < 262144)              { s = Wm; off = i - 196608; }
    else if (i < 524288)              { s = W1; off = i - 262144; }
    else                              { s = W2; off = i - 524288; }
    wb[i] = f2bf(s[off]);
}

// ---------------- MFMA GEMM body ----------------
// modes: 0 f32 [o][n] (y); 1 bf16 qk-layout [h][n][dd] (qb); 2 fp16 v-layout [h][dd][m] (vb);
//        3 hcat[n][512] at c+256; 4 relu bf16 [n][512]; 5 kb swizzled [h][m][ddswz]
template<int KK>
__device__ __forceinline__ void gemm_body(const unsigned short* __restrict__ wb,
                                          const float* __restrict__ bias,
                                          const unsigned short* __restrict__ xt,
                                          void* __restrict__ out, int mode,
                                          int bx, int by) {
    const int tid = threadIdx.x, w = tid >> 6, lane = tid & 63;
    const int lg = lane >> 4, lr = lane & 15;
    const int o_base = by * 64 + w * 16;
    const int n_base = bx * 64;
    f32x4 acc[4];
    #pragma unroll
    for (int j = 0; j < 4; j++) acc[j] = (f32x4){0.f, 0.f, 0.f, 0.f};
    const unsigned short* wrow = wb + (size_t)(o_base + lr) * KK + lg * 8;
    const unsigned short* xrow = xt + (size_t)(n_base + lr) * KK + lg * 8;
    #pragma unroll
    for (int k0 = 0; k0 < KK; k0 += 32) {
        bf16x8 af = *(const bf16x8*)(wrow + k0);
        #pragma unroll
        for (int j = 0; j < 4; j++) {
            bf16x8 bfr = *(const bf16x8*)(xrow + (size_t)j * 16 * KK + k0);
            acc[j] = MFMA_BF16(af, bfr, acc[j]);
        }
    }
    float bv[4];
    #pragma unroll
    for (int r = 0; r < 4; r++) bv[r] = bias[o_base + lg * 4 + r];
    #pragma unroll
    for (int j = 0; j < 4; j++) {
        #pragma unroll
        for (int r = 0; r < 4; r++) {
            int o = o_base + lg * 4 + r;
            int n = n_base + j * 16 + lr;
            float v = acc[j][r] + bv[r];
            if (mode == 0) {
                ((float*)out)[(size_t)o * Nn + n] = v;
            } else if (mode == 1) {
                ((unsigned short*)out)[(((size_t)(o & 3)) * Nn + n) * 64 + (o >> 2)] = f2bf(v);
            } else if (mode == 2) {
                union { _Float16 h; unsigned short u; } cv; cv.h = (_Float16)v;
                ((unsigned short*)out)[(((size_t)(o & 3)) * 64 + (o >> 2)) * Mq + n] = cv.u;
            } else if (mode == 3) {
                ((unsigned short*)out)[(size_t)n * 512 + 256 + o] = f2bf(v);
            } else if (mode == 4) {
                ((unsigned short*)out)[(size_t)n * 512 + o] = f2bf(fmaxf(v, 0.f));
            } else {
                int dd = o >> 2, hh = o & 3, g = dd >> 3, pos = dd & 7;
                int slot = g ^ (n & 7);
                ((unsigned short*)out)[(((size_t)hh * Mq + n)) * 64 + slot * 8 + pos] = f2bf(v);
            }
        }
    }
}

template<int KK>
__global__ __launch_bounds__(256) void k_mgemm(const unsigned short* __restrict__ wb,
                                               const float* __restrict__ bias,
                                               const unsigned short* __restrict__ xt,
                                               void* __restrict__ out, int mode) {
    gemm_body<KK>(wb, bias, xt, out, mode, blockIdx.x, blockIdx.y);
}

__global__ __launch_bounds__(256) void k_qkv(const unsigned short* __restrict__ wb,
                                             const float* __restrict__ bq,
                                             const float* __restrict__ bk,
                                             const float* __restrict__ bv,
                                             const unsigned short* __restrict__ xt,
                                             const unsigned short* __restrict__ st,
                                             void* __restrict__ qb, void* __restrict__ kb,
                                             void* __restrict__ vb) {
    const int z = blockIdx.z;
    const float* bias = (z == 0) ? bq : ((z == 1) ? bk : bv);
    const unsigned short* X = (z == 0) ? xt : st;
    void* out = (z == 0) ? qb : ((z == 1) ? kb : vb);
    int mode = (z == 0) ? 1 : ((z == 1) ? 5 : 2);
    gemm_body<256>(wb + z * 65536, bias, X, out, mode, blockIdx.x, blockIdx.y);
}

// ---------------- score sweep: PHASE 0 = min + class maxes; PHASE 1 = weights ----------------
// grid (32, 8), 512 threads. Block: n128 (8 waves x n16, all heads), m512, LDS-staged K.
template<int PHASE>
__global__ __launch_bounds__(512) void k_score(
    const unsigned short* __restrict__ qb, const unsigned short* __restrict__ kb,
    const unsigned long long* __restrict__ bits,
    const float* __restrict__ sminp,
    float* __restrict__ stats, float* __restrict__ partial,
    float* __restrict__ wout) {
    __shared__ unsigned short kbuf[2][8192];   // [buf][h][m32][64] 32KB
    const int tid = threadIdx.x;
    const int w = tid >> 6, lane = tid & 63;
    const int lg = lane >> 4, lr = lane & 15;
    const int n0 = blockIdx.x * 128 + w * 16;
    const int mb = blockIdx.y;
    const int m0 = mb * 512;

    bf16x8 qf[4][2];
    #pragma unroll
    for (int h = 0; h < 4; h++)
        #pragma unroll
        for (int kh = 0; kh < 2; kh++)
            qf[h][kh] = *(const bf16x8*)(qb + (((size_t)h * Nn + n0 + lr) << 6) + kh*32 + lg*8);

    float smin = 0.f;
    if (PHASE) smin = *sminp;

    // staging pieces: thread covers lin = tid and 512+tid
    const int h0 = tid >> 8, q0 = tid & 255;
    const unsigned short* src0 = kb + (((size_t)h0 * Mq + m0) << 6) + q0 * 8;
    const unsigned short* src1 = kb + (((size_t)(h0 + 2) * Mq + m0) << 6) + q0 * 8;
    unsigned short* dst0 = &kbuf[0][h0 * 2048 + q0 * 8];
    unsigned short* dst1 = &kbuf[0][(h0 + 2) * 2048 + q0 * 8];

    float mn = INFINITY;
    float mx1[4], mx0[4];
    #pragma unroll
    for (int h = 0; h < 4; h++) { mx1[h] = -INFINITY; mx0[h] = -INFINITY; }

    const unsigned long long* brow = bits + (((size_t)(n0 + lr)) << 6) + (m0 >> 6);
    unsigned long long bw = 0ull;

    bf16x8 r0 = *(const bf16x8*)(src0);
    bf16x8 r1 = *(const bf16x8*)(src1);
    *(bf16x8*)dst0 = r0;
    *(bf16x8*)dst1 = r1;
    __syncthreads();
    r0 = *(const bf16x8*)(src0 + 2048);
    r1 = *(const bf16x8*)(src1 + 2048);

    for (int t = 0; t < 16; t++) {
        const unsigned short* kB = &kbuf[t & 1][0];
        const int mch = m0 + t * 32;
        if ((t & 1) == 0) bw = brow[t >> 1];
        #pragma unroll
        for (int mi = 0; mi < 2; mi++) {
            const int rowoff = (mi * 16 + lr) * 64;
            const int shb = (t & 1) * 32 + mi * 16 + lg * 4;
            f32x4 ssum = (f32x4){0.f, 0.f, 0.f, 0.f};
            #pragma unroll
            for (int h = 0; h < 4; h++) {
                bf16x8 a0 = *(const bf16x8*)(kB + h*2048 + rowoff + ((lg ^ (lr & 7)) << 3));
                bf16x8 a1 = *(const bf16x8*)(kB + h*2048 + rowoff + (((lg + 4) ^ (lr & 7)) << 3));
                f32x4 acc = (f32x4){0.f, 0.f, 0.f, 0.f};
                acc = MFMA_BF16(a0, qf[h][0], acc);
                acc = MFMA_BF16(a1, qf[h][1], acc);
                if (PHASE == 0) {
                    #pragma unroll
                    for (int r = 0; r < 4; r++) {
                        float v = acc[r] * 0.125f;
                        mn = fminf(mn, v);
                        bool b = (bw >> (shb + r)) & 1ull;
                        mx1[h] = fmaxf(mx1[h], b ? v : -INFINITY);
                        mx0[h] = fmaxf(mx0[h], b ? -INFINITY : v);
                    }
                } else {
                    ssum += acc;
                }
            }
            if (PHASE == 1) {
                f32x4 wv;
                #pragma unroll
                for (int r = 0; r < 4; r++) {
                    bool b = (bw >> (shb + r)) & 1ull;
                    wv[r] = ssum[r] * 0.03125f + (b ? 0.f : smin);
                }
                *(f32x4*)(wout + (size_t)(n0 + lr) * Mq + mch + mi * 16 + lg * 4) = wv;
            }
        }
        if (t < 15) {
            *(bf16x8*)(dst0 + (((t + 1) & 1) ? 8192 : 0)) = r0;
            *(bf16x8*)(dst1 + (((t + 1) & 1) ? 8192 : 0)) = r1;
        }
        __syncthreads();
        if (t < 14) {
            r0 = *(const bf16x8*)(src0 + (size_t)(t + 2) * 2048);
            r1 = *(const bf16x8*)(src1 + (size_t)(t + 2) * 2048);
        }
    }

    if (PHASE == 0) {
        #pragma unroll
        for (int h = 0; h < 4; h++) {
            mx1[h] = fmaxf(mx1[h], __shfl_xor(mx1[h], 16));
            mx1[h] = fmaxf(mx1[h], __shfl_xor(mx1[h], 32));
            mx0[h] = fmaxf(mx0[h], __shfl_xor(mx0[h], 16));
            mx0[h] = fmaxf(mx0[h], __shfl_xor(mx0[h], 32));
        }
        if (lane < 16) {
            #pragma unroll
            for (int h = 0; h < 4; h++) {
                size_t row = (size_t)h * Nn + n0 + lane;
                stats[row * 16 + mb * 2 + 0] = mx1[h];
                stats[row * 16 + mb * 2 + 1] = mx0[h];
            }
        }
        for (int off = 1; off < 64; off <<= 1) mn = fminf(mn, __shfl_xor(mn, off));
        __shared__ float wmin[8];
        if (lane == 0) wmin[w] = mn;
        __syncthreads();
        if (tid == 0) {
            float m2 = wmin[0];
            #pragma unroll
            for (int i = 1; i < 8; i++) m2 = fminf(m2, wmin[i]);
            partial[blockIdx.x * 8 + mb] = m2;
        }
    }
}

__global__ void k_minreduce(const float* __restrict__ partial, float* __restrict__ smin) {
    const int tid = threadIdx.x;
    float mn = partial[tid];
    __shared__ float red[256];
    red[tid] = mn;
    __syncthreads();
    for (int st = 128; st > 0; st >>= 1) {
        if (tid < st) red[tid] = fminf(red[tid], red[tid + st]);
        __syncthreads();
    }
    if (tid == 0) *smin = red[0];
}

__global__ void k_rowfix(const float* __restrict__ stats, const float* __restrict__ sminp,
                         float* __restrict__ mtarr) {
    int row = blockIdx.x * 256 + threadIdx.x;
    float smin = *sminp;
    float mt = -INFINITY;
    #pragma unroll
    for (int mb = 0; mb < 8; mb++) {
        float a = stats[(size_t)row * 16 + mb * 2];
        float b = stats[(size_t)row * 16 + mb * 2 + 1];
        mt = fmaxf(mt, fmaxf(a, b + smin));
    }
    mtarr[row] = mt;
}

// ---------------- flash PV: grid (8, 32=h4*mb4*dh2), 512 threads ----------------
__global__ __launch_bounds__(512) void k_pv(
    const unsigned short* __restrict__ qb, const unsigned short* __restrict__ kb,
    const unsigned short* __restrict__ vbh,
    const unsigned long long* __restrict__ bits,
    const float* __restrict__ sminp, const float* __restrict__ mtarr,
    float* __restrict__ denp, unsigned short* __restrict__ opart) {
    __shared__ unsigned short kbuf[2][4096];   // [buf][m64][64] 16KB
    const int tid = threadIdx.x;
    const int w = tid >> 6, lane = tid & 63;
    const int lg = lane >> 4, lr = lane & 15;
    const int h = blockIdx.y & 3, mb = (blockIdx.y >> 2) & 3, dh = blockIdx.y >> 4;
    const int n0 = blockIdx.x * 512 + w * 64;
    const int m0 = mb * 1024;
    const float smin = *sminp;

    bf16x8 qf[4][2];
    float mt[4];
    #pragma unroll
    for (int ns = 0; ns < 4; ns++) {
        #pragma unroll
        for (int kh = 0; kh < 2; kh++)
            qf[ns][kh] = *(const bf16x8*)(qb + (((size_t)h * Nn + n0 + ns*16 + lr) << 6) + kh*32 + lg*8);
        mt[ns] = mtarr[(size_t)h * Nn + n0 + ns*16 + lr];
    }

    f32x4 oacc[4][2];
    float dsum[4];
    #pragma unroll
    for (int ns = 0; ns < 4; ns++) {
        oacc[ns][0] = (f32x4){0.f,0.f,0.f,0.f};
        oacc[ns][1] = (f32x4){0.f,0.f,0.f,0.f};
        dsum[ns] = 0.f;
    }

    const unsigned short* ksrc = kb + (((size_t)h * Mq + m0) << 6) + tid * 8;
    bf16x8 r0 = *(const bf16x8*)(ksrc);
    *(bf16x8*)&kbuf[0][tid * 8] = r0;
    __syncthreads();
    r0 = *(const bf16x8*)(ksrc + 4096);

    const unsigned short* vrow0 = vbh + ((size_t)(h * 64 + dh * 32 + lr)) * Mq;
    const unsigned short* vrow1 = vbh + ((size_t)(h * 64 + dh * 32 + 16 + lr)) * Mq;

    for (int t = 0; t < 16; t++) {
        const unsigned short* kB = &kbuf[t & 1][0];
        const int mch = m0 + t * 64;
        unsigned long long bw[4];
        #pragma unroll
        for (int ns = 0; ns < 4; ns++)
            bw[ns] = bits[(((size_t)(n0 + ns*16 + lr)) << 6) + (mch >> 6)];
        #pragma unroll
        for (int mi = 0; mi < 4; mi++) {
            const int rowoff = (mi * 16 + lr) * 64;
            bf16x8 a0 = *(const bf16x8*)(kB + rowoff + ((lg ^ (lr & 7)) << 3));
            bf16x8 a1 = *(const bf16x8*)(kB + rowoff + (((lg + 4) ^ (lr & 7)) << 3));
            f16x4 vf0 = *(const f16x4*)(vrow0 + mch + mi * 16 + lg * 4);
            f16x4 vf1 = *(const f16x4*)(vrow1 + mch + mi * 16 + lg * 4);
            const int shb = mi * 16 + lg * 4;
            #pragma unroll
            for (int ns = 0; ns < 4; ns++) {
                f32x4 acc = (f32x4){0.f,0.f,0.f,0.f};
                acc = MFMA_BF16(a0, qf[ns][0], acc);
                acc = MFMA_BF16(a1, qf[ns][1], acc);
                f16x4 pf;
                float dloc = 0.f;
                #pragma unroll
                for (int r = 0; r < 4; r++) {
                    bool b = (bw[ns] >> (shb + r)) & 1ull;
                    float v = acc[r] * 0.125f + (b ? 0.f : smin);
                    float p = __expf(v - mt[ns]);
                    dloc += p;
                    pf[r] = (_Float16)p;
                }
                dsum[ns] += dloc;
                oacc[ns][0] = MFMA_F16x16(pf, vf0, oacc[ns][0]);
                oacc[ns][1] = MFMA_F16x16(pf, vf1, oacc[ns][1]);
            }
        }
        if (t < 15) *(bf16x8*)&kbuf[(t + 1) & 1][tid * 8] = r0;
        __syncthreads();
        if (t < 14) r0 = *(const bf16x8*)(ksrc + (size_t)(t + 2) * 4096);
    }

    #pragma unroll
    for (int ns = 0; ns < 4; ns++) {
        dsum[ns] += __shfl_xor(dsum[ns], 16);
        dsum[ns] += __shfl_xor(dsum[ns], 32);
    }
    if (dh == 0 && lane < 16) {
        #pragma unroll
        for (int ns = 0; ns < 4; ns++)
            denp[((size_t)h * Nn + n0 + ns*16 + lane) * 4 + mb] = dsum[ns];
    }
    unsigned short* op = opart + (size_t)mb * (Dm * Nn);
    #pragma unroll
    for (int ns = 0; ns < 4; ns++)
        #pragma unroll
        for (int ds = 0; ds < 2; ds++) {
            int c = (dh * 32 + ds * 16 + lr) * 4 + h;
            int n = n0 + ns * 16 + lg * 4;
            unsigned long long pk =
                (unsigned long long)f2bf(oacc[ns][ds][0]) |
                ((unsigned long long)f2bf(oacc[ns][ds][1]) << 16) |
                ((unsigned long long)f2bf(oacc[ns][ds][2]) << 32) |
                ((unsigned long long)f2bf(oacc[ns][ds][3]) << 48);
            *(unsigned long long*)&op[(size_t)c * Nn + n] = pk;
        }
}

// ---------------- finish: sum partials, normalize, transpose -> attnT[n][c] bf16 ----------------
__global__ __launch_bounds__(256) void k_finish(const unsigned short* __restrict__ opart,
                                                const float* __restrict__ denp,
                                                unsigned short* __restrict__ attnT) {
    __shared__ float t[64][65];
    const int cb = blockIdx.y * 64, nb = blockIdx.x * 64;
    const int tid = threadIdx.x;
    #pragma unroll
    for (int e = 0; e < 16; e++) {
        int idx = e * 256 + tid;
        int c_l = idx >> 6, n_l = idx & 63;
        int c = cb + c_l, n = nb + n_l;
        float s = 0.f;
        #pragma unroll
        for (int y = 0; y < 4; y++)
            s += bf2f(opart[(size_t)y * (Dm*Nn) + (size_t)c * Nn + n]);
        size_t row = (size_t)(c & 3) * Nn + n;
        float d = denp[row*4] + denp[row*4+1] + denp[row*4+2] + denp[row*4+3];
        t[c_l][n_l] = s / d;
    }
    __syncthreads();
    #pragma unroll
    for (int e = 0; e < 16; e++) {
        int idx = e * 256 + tid;
        int n_l = idx >> 6, c_l = idx & 63;
        attnT[(size_t)(nb + n_l) * 256 + cb + c_l] = f2bf(t[c_l][n_l]);
    }
}

extern "C" void kernel_launch(void* const* d_in, const int* in_sizes, int n_in,
                              void* d_out, int out_size, void* d_ws, size_t ws_size,
                              hipStream_t stream) {
    const float* x      = (const float*)d_in[0];
    const float* source = (const float*)d_in[1];
    const void*  mask   = d_in[3];
    const float* Wq = (const float*)d_in[4];  const float* bq = (const float*)d_in[5];
    const float* Wk = (const float*)d_in[6];  const float* bk = (const float*)d_in[7];
    const float* Wv = (const float*)d_in[8];  const float* bv = (const float*)d_in[9];
    const float* Wm = (const float*)d_in[10]; const float* bm = (const float*)d_in[11];
    const float* W1 = (const float*)d_in[12]; const float* b1 = (const float*)d_in[13];
    const float* W2 = (const float*)d_in[14]; const float* b2 = (const float*)d_in[15];

    float* y    = (float*)d_out;                // [256,4096]
    float* wout = y + (size_t)Dm * Nn;          // [4096,4096]

    char* ws = (char*)d_ws;
    int*   flag  = (int*)(ws + OFF_FLAG);
    float* sminp = (float*)(ws + OFF_SMIN);
    float* part  = (float*)(ws + OFF_PART);
    float* mtarr = (float*)(ws + OFF_MT);
    float* denp  = (float*)(ws + OFF_DENP);
    float* stats = (float*)(ws + OFF_STATS);
    unsigned short* wb    = (unsigned short*)(ws + OFF_WB);
    unsigned char*  bits  = (unsigned char*)(ws + OFF_BITS);
    unsigned short* qb    = (unsigned short*)(ws + OFF_QB);
    unsigned short* kb    = (unsigned short*)(ws + OFF_KB);
    unsigned short* vb    = (unsigned short*)(ws + OFF_VB);
    unsigned short* hcat  = (unsigned short*)(ws + OFF_HCAT);
    unsigned short* attnT = (unsigned short*)(ws + OFF_ATTNT);
    unsigned short* xt    = (unsigned short*)(ws + OFF_XT);
    unsigned short* st    = (unsigned short*)(ws + OFF_ST);
    unsigned short* opart = (unsigned short*)(ws + OFF_OPART);
    unsigned short* h1t   = (unsigned short*)(ws + OFF_H1T);

    k_detect<<<1, 256, 0, stream>>>((const unsigned char*)mask, flag);
    k_maskbits<<<8192, 256, 0, stream>>>(mask, flag, bits);

    k_prep<<<dim3(128, 4), 256, 0, stream>>>(x, xt, hcat);
    k_prep<<<dim3(128, 4), 256, 0, stream>>>(source, st, nullptr);
    k_wcast<<<2560, 256, 0, stream>>>(Wq, Wk, Wv, Wm, W1, W2, wb);

    k_qkv<<<dim3(64, 4, 3), 256, 0, stream>>>(wb, bq, bk, bv, xt, st, qb, kb, vb);

    k_score<0><<<dim3(32, 8), 512, 0, stream>>>(qb, kb, (const unsigned long long*)bits,
                                                nullptr, stats, part, nullptr);
    k_minreduce<<<1, 256, 0, stream>>>(part, sminp);
    k_rowfix<<<64, 256, 0, stream>>>(stats, sminp, mtarr);

    k_score<1><<<dim3(32, 8), 512, 0, stream>>>(qb, kb, (const unsigned long long*)bits,
                                                sminp, nullptr, nullptr, wout);

    k_pv<<<dim3(8, 32), 512, 0, stream>>>(qb, kb, vb, (const unsigned long long*)bits,
                                          sminp, mtarr, denp, opart);
    k_finish<<<dim3(64, 4), 256, 0, stream>>>(opart, denp, attnT);

    k_mgemm<256><<<dim3(64, 4), 256, 0, stream>>>(wb + WOFF_M, bm, attnT, hcat, 3);
    k_mgemm<512><<<dim3(64, 8), 256, 0, stream>>>(wb + WOFF_1, b1, hcat, h1t, 4);
    k_mgemm<512><<<dim3(64, 4), 256, 0, stream>>>(wb + WOFF_2, b2, h1t, y, 0);
}

// Round 5
// 208.130 us; speedup vs baseline: 7.2335x; 1.1306x over previous
//
#include <hip/hip_runtime.h>
#include <hip/hip_bf16.h>
#include <math.h>

#define Dm 256
#define Hh 4
#define Nn 4096
#define Mq 4096

typedef __attribute__((ext_vector_type(8))) short bf16x8;
typedef __attribute__((ext_vector_type(4))) float f32x4;
typedef _Float16 __attribute__((ext_vector_type(4))) f16x4;

#define MFMA_BF16(a,b,c) __builtin_amdgcn_mfma_f32_16x16x32_bf16(a,b,c,0,0,0)
#define MFMA_F16x16(a,b,c) __builtin_amdgcn_mfma_f32_16x16x16f16(a,b,c,0,0,0)

#define MB (1u<<20)
// ---- workspace layout (bytes); 32MB proven ----
#define OFF_FLAG  0
#define OFF_SMIN  64
#define OFF_PART  128                 // 256 f32
#define OFF_KMAX  2048                // 4 u32
#define OFF_MT    4096                // 16384 f32 (64KB)
#define OFF_DENP  (128u<<10)          // 16384*4 f32 (256KB)
#define OFF_WB    (3u*MB/2)           // 655360 bf16 (1.25MB)
#define OFF_BITS  (3u*MB)             // 2MB bitmask
#define OFF_QB    (5u*MB)             // bf16 [h][n][64] 2MB
#define OFF_KB    (7u*MB)             // bf16 [h][m][64] swizzled 2MB
#define OFF_VB    (9u*MB)             // fp16 [h][dd][m] 2MB
#define OFF_HCAT  (11u*MB)            // bf16 [n][512] 4MB
#define OFF_ATTNT (15u*MB)            // bf16 [n][256] 2MB
// overlap region (xt/st die after QKV; opart dies before h1t written)
#define OFF_XT    (17u*MB)            // bf16 [n][256] 2MB
#define OFF_ST    (19u*MB)            // bf16 [n][256] 2MB
#define OFF_OPART (17u*MB)            // bf16 [4][c][n] 8MB -> ends 25MB
#define OFF_H1T   (17u*MB)            // bf16 [n][512] 4MB

#define WOFF_Q  0
#define WOFF_K  65536
#define WOFF_V  131072
#define WOFF_M  196608
#define WOFF_1  262144
#define WOFF_2  524288

__device__ __forceinline__ unsigned short f2bf(float x) {
    unsigned u = __float_as_uint(x);
    u += 0x7FFF + ((u >> 16) & 1);
    return (unsigned short)(u >> 16);
}
__device__ __forceinline__ float bf2f(unsigned short b) {
    return __uint_as_float(((unsigned)b) << 16);
}

// ---------------- mask dtype detection ----------------
__global__ void k_detect(const unsigned char* __restrict__ mb, int* __restrict__ flag) {
    __shared__ int c[5];
    if (threadIdx.x < 5) c[threadIdx.x] = 0;
    __syncthreads();
    for (int i = threadIdx.x; i < 16384; i += blockDim.x) {
        unsigned char b = mb[i];
        if (b) {
            atomicAdd(&c[i & 3], 1);
            if ((i & 7) == 4) atomicAdd(&c[4], 1);
        }
    }
    __syncthreads();
    if (threadIdx.x == 0) {
        int f;
        if (c[3] > 0 && c[0] == 0)          f = 3;
        else if (c[1] | c[2] | c[3])        f = 1;
        else if (c[4] > 0)                  f = 0;
        else                                f = 2;
        *flag = f;
    }
}

// ---------------- mask -> bitmask ----------------
__global__ void k_maskbits(const void* __restrict__ mp, const int* __restrict__ flagp,
                           unsigned char* __restrict__ bits) {
    size_t i = (size_t)blockIdx.x * 256 + threadIdx.x;
    const int flag = *flagp;
    size_t base = i * 8;
    unsigned b = 0;
    if (flag == 1) {
        unsigned long long u = *(const unsigned long long*)((const unsigned char*)mp + base);
        #pragma unroll
        for (int j = 0; j < 8; j++) b |= (unsigned)(((u >> (8*j)) & 0xFFull) != 0ull) << j;
    } else if (flag == 0) {
        const int* p = (const int*)mp;
        #pragma unroll
        for (int j = 0; j < 8; j++) b |= (unsigned)(p[base + j] != 0) << j;
    } else if (flag == 3) {
        const float* p = (const float*)mp;
        #pragma unroll
        for (int j = 0; j < 8; j++) b |= (unsigned)(p[base + j] != 0.0f) << j;
    } else {
        const unsigned long long* p = (const unsigned long long*)mp;
        #pragma unroll
        for (int j = 0; j < 8; j++) b |= (unsigned)(p[base + j] != 0ull) << j;
    }
    bits[i] = (unsigned char)b;
}

// ---------------- transpose-cast f32 [c][n] -> bf16 [n][c] (+optional hcat copy) ----------------
__global__ __launch_bounds__(256) void k_prep(const float* __restrict__ src,
                                              unsigned short* __restrict__ dst,
                                              unsigned short* __restrict__ dst2) {
    const int l = threadIdx.x & 63, g = threadIdx.x >> 6;
    const int c = blockIdx.y * 64 + l;
    const int n0 = blockIdx.x * 32 + g * 8;
    float4 v0 = *(const float4*)(src + (size_t)c * Nn + n0);
    float4 v1 = *(const float4*)(src + (size_t)c * Nn + n0 + 4);
    float vv[8] = {v0.x, v0.y, v0.z, v0.w, v1.x, v1.y, v1.z, v1.w};
    #pragma unroll
    for (int j = 0; j < 8; j++) {
        unsigned short b = f2bf(vv[j]);
        dst[(size_t)(n0 + j) * 256 + c] = b;
        if (dst2) dst2[(size_t)(n0 + j) * 512 + c] = b;
    }
}

// ---------------- cast all weights to bf16 ----------------
__global__ void k_wcast(const float* __restrict__ Wq, const float* __restrict__ Wk,
                        const float* __restrict__ Wv, const float* __restrict__ Wm,
                        const float* __restrict__ W1, const float* __restrict__ W2,
                        unsigned short* __restrict__ wb) {
    size_t i = (size_t)blockIdx.x * 256 + threadIdx.x;
    const float* s; size_t off;
    if      (i < 65536)               { s = Wq; off = i; }
    else if (i < 131072)              { s = Wk; off = i - 65536; }
    else if (i < 196608)              { s = Wv; off = i - 131072; }
    else if (i < 262144)              { s = Wm; off = i - 196608; }
    else if (i < 524288)              { s = W1; off = i - 262144; }
    else                              { s = W2; off = i - 524288; }
    wb[i] = f2bf(s[off]);
}

// ---------------- MFMA GEMM body ----------------
// modes: 0 f32 [o][n] (y); 1 bf16 qk-layout [h][n][dd] (qb); 2 fp16 v-layout [h][dd][m] (vb);
//        3 hcat[n][512] at c+256; 4 relu bf16 [n][512]; 5 kb swizzled [h][m][ddswz]
template<int KK>
__device__ __forceinline__ void gemm_body(const unsigned short* __restrict__ wb,
                                          const float* __restrict__ bias,
                                          const unsigned short* __restrict__ xt,
                                          void* __restrict__ out, int mode,
                                          int bx, int by) {
    const int tid = threadIdx.x, w = tid >> 6, lane = tid & 63;
    const int lg = lane >> 4, lr = lane & 15;
    const int o_base = by * 64 + w * 16;
    const int n_base = bx * 64;
    f32x4 acc[4];
    #pragma unroll
    for (int j = 0; j < 4; j++) acc[j] = (f32x4){0.f, 0.f, 0.f, 0.f};
    const unsigned short* wrow = wb + (size_t)(o_base + lr) * KK + lg * 8;
    const unsigned short* xrow = xt + (size_t)(n_base + lr) * KK + lg * 8;
    #pragma unroll
    for (int k0 = 0; k0 < KK; k0 += 32) {
        bf16x8 af = *(const bf16x8*)(wrow + k0);
        #pragma unroll
        for (int j = 0; j < 4; j++) {
            bf16x8 bfr = *(const bf16x8*)(xrow + (size_t)j * 16 * KK + k0);
            acc[j] = MFMA_BF16(af, bfr, acc[j]);
        }
    }
    float bv[4];
    #pragma unroll
    for (int r = 0; r < 4; r++) bv[r] = bias[o_base + lg * 4 + r];
    #pragma unroll
    for (int j = 0; j < 4; j++) {
        #pragma unroll
        for (int r = 0; r < 4; r++) {
            int o = o_base + lg * 4 + r;
            int n = n_base + j * 16 + lr;
            float v = acc[j][r] + bv[r];
            if (mode == 0) {
                ((float*)out)[(size_t)o * Nn + n] = v;
            } else if (mode == 1) {
                ((unsigned short*)out)[(((size_t)(o & 3)) * Nn + n) * 64 + (o >> 2)] = f2bf(v);
            } else if (mode == 2) {
                union { _Float16 h; unsigned short u; } cv; cv.h = (_Float16)v;
                ((unsigned short*)out)[(((size_t)(o & 3)) * 64 + (o >> 2)) * Mq + n] = cv.u;
            } else if (mode == 3) {
                ((unsigned short*)out)[(size_t)n * 512 + 256 + o] = f2bf(v);
            } else if (mode == 4) {
                ((unsigned short*)out)[(size_t)n * 512 + o] = f2bf(fmaxf(v, 0.f));
            } else {
                int dd = o >> 2, hh = o & 3, g = dd >> 3, pos = dd & 7;
                int slot = g ^ (n & 7);
                ((unsigned short*)out)[(((size_t)hh * Mq + n)) * 64 + slot * 8 + pos] = f2bf(v);
            }
        }
    }
}

template<int KK>
__global__ __launch_bounds__(256) void k_mgemm(const unsigned short* __restrict__ wb,
                                               const float* __restrict__ bias,
                                               const unsigned short* __restrict__ xt,
                                               void* __restrict__ out, int mode) {
    gemm_body<KK>(wb, bias, xt, out, mode, blockIdx.x, blockIdx.y);
}

__global__ __launch_bounds__(256) void k_qkv(const unsigned short* __restrict__ wb,
                                             const float* __restrict__ bq,
                                             const float* __restrict__ bk,
                                             const float* __restrict__ bv,
                                             const unsigned short* __restrict__ xt,
                                             const unsigned short* __restrict__ st,
                                             void* __restrict__ qb, void* __restrict__ kb,
                                             void* __restrict__ vb) {
    const int z = blockIdx.z;
    const float* bias = (z == 0) ? bq : ((z == 1) ? bk : bv);
    const unsigned short* X = (z == 0) ? xt : st;
    void* out = (z == 0) ? qb : ((z == 1) ? kb : vb);
    int mode = (z == 0) ? 1 : ((z == 1) ? 5 : 2);
    gemm_body<256>(wb + z * 65536, bias, X, out, mode, blockIdx.x, blockIdx.y);
}

// ---------------- norm-based row-max bound ----------------
__global__ void k_init(unsigned* __restrict__ kmax) {
    if (threadIdx.x < 4) kmax[threadIdx.x] = 0u;
}

__global__ __launch_bounds__(256) void k_knorm(const unsigned short* __restrict__ kb,
                                               unsigned* __restrict__ kmax) {
    const int h = blockIdx.y;
    const int m = blockIdx.x * 256 + threadIdx.x;
    const unsigned short* row = kb + ((size_t)(h * Mq + m) << 6);
    float s = 0.f;
    #pragma unroll
    for (int i = 0; i < 64; i++) { float v = bf2f(row[i]); s = fmaf(v, v, s); }
    __shared__ float red[256];
    red[threadIdx.x] = s;
    __syncthreads();
    for (int st = 128; st > 0; st >>= 1) {
        if (threadIdx.x < st) red[threadIdx.x] = fmaxf(red[threadIdx.x], red[threadIdx.x + st]);
        __syncthreads();
    }
    if (threadIdx.x == 0) atomicMax(kmax + h, __float_as_uint(red[0]));
}

__global__ __launch_bounds__(256) void k_qnorm(const unsigned short* __restrict__ qb,
                                               const unsigned* __restrict__ kmax,
                                               float* __restrict__ mtarr) {
    const int row = blockIdx.x * 256 + threadIdx.x;   // h*Nn + n
    const unsigned short* qr = qb + ((size_t)row << 6);
    float s = 0.f;
    #pragma unroll
    for (int i = 0; i < 64; i++) { float v = bf2f(qr[i]); s = fmaf(v, v, s); }
    float k2 = __uint_as_float(kmax[row >> 12]);
    mtarr[row] = sqrtf(s * k2) * 0.125f;   // |q|*|k|max/8 >= rowmax
}

// ---------------- global min of raw scores ----------------
// grid (32, 8), 512 threads; per wave n16 all heads; m512 per block, LDS-staged K.
__global__ __launch_bounds__(512) void k_min(
    const unsigned short* __restrict__ qb, const unsigned short* __restrict__ kb,
    float* __restrict__ partial) {
    __shared__ unsigned short kbuf[2][8192];   // [buf][h][m32][64] 32KB
    const int tid = threadIdx.x;
    const int w = tid >> 6, lane = tid & 63;
    const int lg = lane >> 4, lr = lane & 15;
    const int n0 = blockIdx.x * 128 + w * 16;
    const int m0 = blockIdx.y * 512;

    bf16x8 qf[4][2];
    #pragma unroll
    for (int h = 0; h < 4; h++)
        #pragma unroll
        for (int kh = 0; kh < 2; kh++)
            qf[h][kh] = *(const bf16x8*)(qb + (((size_t)h * Nn + n0 + lr) << 6) + kh*32 + lg*8);

    const int h0 = tid >> 8, q0 = tid & 255;
    const unsigned short* src0 = kb + (((size_t)h0 * Mq + m0) << 6) + q0 * 8;
    const unsigned short* src1 = kb + (((size_t)(h0 + 2) * Mq + m0) << 6) + q0 * 8;
    unsigned short* dst0 = &kbuf[0][h0 * 2048 + q0 * 8];
    unsigned short* dst1 = &kbuf[0][(h0 + 2) * 2048 + q0 * 8];

    float mn = INFINITY;

    bf16x8 r0 = *(const bf16x8*)(src0);
    bf16x8 r1 = *(const bf16x8*)(src1);
    *(bf16x8*)dst0 = r0;
    *(bf16x8*)dst1 = r1;
    __syncthreads();
    r0 = *(const bf16x8*)(src0 + 2048);
    r1 = *(const bf16x8*)(src1 + 2048);

    for (int t = 0; t < 16; t++) {
        const unsigned short* kB = &kbuf[t & 1][0];
        #pragma unroll
        for (int mi = 0; mi < 2; mi++) {
            const int rowoff = (mi * 16 + lr) * 64;
            #pragma unroll
            for (int h = 0; h < 4; h++) {
                bf16x8 a0 = *(const bf16x8*)(kB + h*2048 + rowoff + ((lg ^ (lr & 7)) << 3));
                bf16x8 a1 = *(const bf16x8*)(kB + h*2048 + rowoff + (((lg + 4) ^ (lr & 7)) << 3));
                f32x4 acc = (f32x4){0.f, 0.f, 0.f, 0.f};
                acc = MFMA_BF16(a0, qf[h][0], acc);
                acc = MFMA_BF16(a1, qf[h][1], acc);
                mn = fminf(mn, fminf(fminf(acc[0], acc[1]), fminf(acc[2], acc[3])));
            }
        }
        if (t < 15) {
            *(bf16x8*)(dst0 + (((t + 1) & 1) ? 8192 : 0)) = r0;
            *(bf16x8*)(dst1 + (((t + 1) & 1) ? 8192 : 0)) = r1;
        }
        __syncthreads();
        if (t < 14) {
            r0 = *(const bf16x8*)(src0 + (size_t)(t + 2) * 2048);
            r1 = *(const bf16x8*)(src1 + (size_t)(t + 2) * 2048);
        }
    }

    for (int off = 1; off < 64; off <<= 1) mn = fminf(mn, __shfl_xor(mn, off));
    __shared__ float wmin[8];
    if (lane == 0) wmin[w] = mn;
    __syncthreads();
    if (tid == 0) {
        float m2 = wmin[0];
        #pragma unroll
        for (int i = 1; i < 8; i++) m2 = fminf(m2, wmin[i]);
        partial[blockIdx.x * 8 + blockIdx.y] = m2 * 0.125f;
    }
}

__global__ void k_minreduce(const float* __restrict__ partial, float* __restrict__ smin) {
    const int tid = threadIdx.x;
    float mn = partial[tid];
    __shared__ float red[256];
    red[tid] = mn;
    __syncthreads();
    for (int st = 128; st > 0; st >>= 1) {
        if (tid < st) red[tid] = fminf(red[tid], red[tid + st]);
        __syncthreads();
    }
    if (tid == 0) *smin = red[0];
}

// ---------------- weights: full-K head-summed GEMM + mask epilogue ----------------
// grid (32, 8), 512 threads; same staging as k_min.
__global__ __launch_bounds__(512) void k_wout(
    const unsigned short* __restrict__ qb, const unsigned short* __restrict__ kb,
    const unsigned long long* __restrict__ bits,
    const float* __restrict__ sminp, float* __restrict__ wout) {
    __shared__ unsigned short kbuf[2][8192];
    const int tid = threadIdx.x;
    const int w = tid >> 6, lane = tid & 63;
    const int lg = lane >> 4, lr = lane & 15;
    const int n0 = blockIdx.x * 128 + w * 16;
    const int m0 = blockIdx.y * 512;
    const float smin = *sminp;

    bf16x8 qf[4][2];
    #pragma unroll
    for (int h = 0; h < 4; h++)
        #pragma unroll
        for (int kh = 0; kh < 2; kh++)
            qf[h][kh] = *(const bf16x8*)(qb + (((size_t)h * Nn + n0 + lr) << 6) + kh*32 + lg*8);

    const int h0 = tid >> 8, q0 = tid & 255;
    const unsigned short* src0 = kb + (((size_t)h0 * Mq + m0) << 6) + q0 * 8;
    const unsigned short* src1 = kb + (((size_t)(h0 + 2) * Mq + m0) << 6) + q0 * 8;
    unsigned short* dst0 = &kbuf[0][h0 * 2048 + q0 * 8];
    unsigned short* dst1 = &kbuf[0][(h0 + 2) * 2048 + q0 * 8];

    const unsigned long long* brow = bits + (((size_t)(n0 + lr)) << 6) + (m0 >> 6);
    unsigned long long bw = 0ull;

    bf16x8 r0 = *(const bf16x8*)(src0);
    bf16x8 r1 = *(const bf16x8*)(src1);
    *(bf16x8*)dst0 = r0;
    *(bf16x8*)dst1 = r1;
    __syncthreads();
    r0 = *(const bf16x8*)(src0 + 2048);
    r1 = *(const bf16x8*)(src1 + 2048);

    for (int t = 0; t < 16; t++) {
        const unsigned short* kB = &kbuf[t & 1][0];
        const int mch = m0 + t * 32;
        if ((t & 1) == 0) bw = brow[t >> 1];
        #pragma unroll
        for (int mi = 0; mi < 2; mi++) {
            const int rowoff = (mi * 16 + lr) * 64;
            f32x4 accA = (f32x4){0.f, 0.f, 0.f, 0.f};
            f32x4 accB = (f32x4){0.f, 0.f, 0.f, 0.f};
            #pragma unroll
            for (int h = 0; h < 2; h++) {
                bf16x8 a0 = *(const bf16x8*)(kB + h*2048 + rowoff + ((lg ^ (lr & 7)) << 3));
                bf16x8 a1 = *(const bf16x8*)(kB + h*2048 + rowoff + (((lg + 4) ^ (lr & 7)) << 3));
                accA = MFMA_BF16(a0, qf[h][0], accA);
                accA = MFMA_BF16(a1, qf[h][1], accA);
            }
            #pragma unroll
            for (int h = 2; h < 4; h++) {
                bf16x8 a0 = *(const bf16x8*)(kB + h*2048 + rowoff + ((lg ^ (lr & 7)) << 3));
                bf16x8 a1 = *(const bf16x8*)(kB + h*2048 + rowoff + (((lg + 4) ^ (lr & 7)) << 3));
                accB = MFMA_BF16(a0, qf[h][0], accB);
                accB = MFMA_BF16(a1, qf[h][1], accB);
            }
            const int shb = (t & 1) * 32 + mi * 16 + lg * 4;
            f32x4 wv;
            #pragma unroll
            for (int r = 0; r < 4; r++) {
                bool b = (bw >> (shb + r)) & 1ull;
                wv[r] = fmaf(accA[r] + accB[r], 0.03125f, b ? 0.f : smin);
            }
            *(f32x4*)(wout + (size_t)(n0 + lr) * Mq + mch + mi * 16 + lg * 4) = wv;
        }
        if (t < 15) {
            *(bf16x8*)(dst0 + (((t + 1) & 1) ? 8192 : 0)) = r0;
            *(bf16x8*)(dst1 + (((t + 1) & 1) ? 8192 : 0)) = r1;
        }
        __syncthreads();
        if (t < 14) {
            r0 = *(const bf16x8*)(src0 + (size_t)(t + 2) * 2048);
            r1 = *(const bf16x8*)(src1 + (size_t)(t + 2) * 2048);
        }
    }
}

// ---------------- flash PV: grid (16, 16=h4*mb4), 512 thr, 8 waves x n32, full dd ----------------
__global__ __launch_bounds__(512) void k_pv(
    const unsigned short* __restrict__ qb, const unsigned short* __restrict__ kb,
    const unsigned short* __restrict__ vbh,
    const unsigned long long* __restrict__ bits,
    const float* __restrict__ sminp, const float* __restrict__ mtarr,
    float* __restrict__ denp, unsigned short* __restrict__ opart) {
    __shared__ unsigned short kbuf[2][4096];   // [buf][m64][64] bf16 8KB
    __shared__ unsigned short vbuf[2][4096];   // [buf][mi4][dd64][m16] f16 8KB
    const int tid = threadIdx.x;
    const int w = tid >> 6, lane = tid & 63;
    const int lg = lane >> 4, lr = lane & 15;
    const int h = blockIdx.y & 3, mb = blockIdx.y >> 2;
    const int n0 = blockIdx.x * 256 + w * 32;
    const int m0 = mb * 1024;
    const float smin = *sminp;
    const float sminc = fmaxf(smin, 0.f);

    bf16x8 qf[2][2];
    float cT[2], cF[2];
    #pragma unroll
    for (int ns = 0; ns < 2; ns++) {
        #pragma unroll
        for (int kh = 0; kh < 2; kh++)
            qf[ns][kh] = *(const bf16x8*)(qb + (((size_t)h * Nn + n0 + ns*16 + lr) << 6) + kh*32 + lg*8);
        float mtE = mtarr[(size_t)h * Nn + n0 + ns*16 + lr] + sminc;
        cT[ns] = -mtE * 1.44269504f;
        cF[ns] = cT[ns] + smin * 1.44269504f;
    }

    f32x4 oacc[2][4];
    #pragma unroll
    for (int ns = 0; ns < 2; ns++)
        #pragma unroll
        for (int ds = 0; ds < 4; ds++)
            oacc[ns][ds] = (f32x4){0.f, 0.f, 0.f, 0.f};
    float dsum[2] = {0.f, 0.f};

    // K staging: thread -> 16B linear; V staging: tid=(dd<<3)|j, coalesced global read
    const unsigned short* ksrc = kb + (((size_t)h * Mq + m0) << 6) + tid * 8;
    const int vj = tid & 7, vdd = tid >> 3;
    const unsigned short* vsrc = vbh + (size_t)(h * 64 + vdd) * Mq + m0 + vj * 8;
    const int vdst = ((vj >> 1) * 64 + vdd) * 16 + (vj & 1) * 8;

    bf16x8 rk = *(const bf16x8*)(ksrc);
    bf16x8 rv = *(const bf16x8*)(vsrc);
    *(bf16x8*)&kbuf[0][tid * 8] = rk;
    *(bf16x8*)&vbuf[0][vdst] = rv;
    __syncthreads();
    rk = *(const bf16x8*)(ksrc + 4096);
    rv = *(const bf16x8*)(vsrc + 64);

    for (int t = 0; t < 16; t++) {
        const unsigned short* kB = &kbuf[t & 1][0];
        const unsigned short* vB = &vbuf[t & 1][0];
        const int mch = m0 + t * 64;
        unsigned long long bw[2];
        #pragma unroll
        for (int ns = 0; ns < 2; ns++)
            bw[ns] = bits[(((size_t)(n0 + ns*16 + lr)) << 6) + (mch >> 6)];
        #pragma unroll
        for (int mi = 0; mi < 4; mi++) {
            const int rowoff = (mi * 16 + lr) * 64;
            bf16x8 a0 = *(const bf16x8*)(kB + rowoff + ((lg ^ (lr & 7)) << 3));
            bf16x8 a1 = *(const bf16x8*)(kB + rowoff + (((lg + 4) ^ (lr & 7)) << 3));
            f16x4 vf[4];
            #pragma unroll
            for (int ds = 0; ds < 4; ds++)
                vf[ds] = *(const f16x4*)&vB[(mi * 64 + ds * 16 + lr) * 16 + lg * 4];
            const int shb = mi * 16 + lg * 4;
            #pragma unroll
            for (int ns = 0; ns < 2; ns++) {
                f32x4 acc = (f32x4){0.f, 0.f, 0.f, 0.f};
                acc = MFMA_BF16(a0, qf[ns][0], acc);
                acc = MFMA_BF16(a1, qf[ns][1], acc);
                f16x4 pf;
                float dloc = 0.f;
                #pragma unroll
                for (int r = 0; r < 4; r++) {
                    bool b = (bw[ns] >> (shb + r)) & 1ull;
                    float p = exp2f(fmaf(acc[r], 0.18033688f, b ? cT[ns] : cF[ns]));
                    dloc += p;
                    pf[r] = (_Float16)p;
                }
                dsum[ns] += dloc;
                #pragma unroll
                for (int ds = 0; ds < 4; ds++)
                    oacc[ns][ds] = MFMA_F16x16(pf, vf[ds], oacc[ns][ds]);
            }
        }
        if (t < 15) {
            *(bf16x8*)&kbuf[(t + 1) & 1][tid * 8] = rk;
            *(bf16x8*)&vbuf[(t + 1) & 1][vdst] = rv;
        }
        __syncthreads();
        if (t < 14) {
            rk = *(const bf16x8*)(ksrc + (size_t)(t + 2) * 4096);
            rv = *(const bf16x8*)(vsrc + (size_t)(t + 2) * 64);
        }
    }

    #pragma unroll
    for (int ns = 0; ns < 2; ns++) {
        dsum[ns] += __shfl_xor(dsum[ns], 16);
        dsum[ns] += __shfl_xor(dsum[ns], 32);
    }
    if (lane < 16) {
        #pragma unroll
        for (int ns = 0; ns < 2; ns++)
            denp[((size_t)h * Nn + n0 + ns*16 + lane) * 4 + mb] = dsum[ns];
    }
    unsigned short* op = opart + (size_t)mb * (Dm * Nn);
    #pragma unroll
    for (int ns = 0; ns < 2; ns++)
        #pragma unroll
        for (int ds = 0; ds < 4; ds++) {
            int c = (ds * 16 + lr) * 4 + h;
            int n = n0 + ns * 16 + lg * 4;
            unsigned long long pk =
                (unsigned long long)f2bf(oacc[ns][ds][0]) |
                ((unsigned long long)f2bf(oacc[ns][ds][1]) << 16) |
                ((unsigned long long)f2bf(oacc[ns][ds][2]) << 32) |
                ((unsigned long long)f2bf(oacc[ns][ds][3]) << 48);
            *(unsigned long long*)&op[(size_t)c * Nn + n] = pk;
        }
}

// ---------------- finish: sum partials, normalize, transpose -> attnT[n][c] bf16 ----------------
__global__ __launch_bounds__(256) void k_finish(const unsigned short* __restrict__ opart,
                                                const float* __restrict__ denp,
                                                unsigned short* __restrict__ attnT) {
    __shared__ float t[64][65];
    const int cb = blockIdx.y * 64, nb = blockIdx.x * 64;
    const int tid = threadIdx.x;
    #pragma unroll
    for (int e = 0; e < 16; e++) {
        int idx = e * 256 + tid;
        int c_l = idx >> 6, n_l = idx & 63;
        int c = cb + c_l, n = nb + n_l;
        float s = 0.f;
        #pragma unroll
        for (int y = 0; y < 4; y++)
            s += bf2f(opart[(size_t)y * (Dm*Nn) + (size_t)c * Nn + n]);
        size_t row = (size_t)(c & 3) * Nn + n;
        float d = denp[row*4] + denp[row*4+1] + denp[row*4+2] + denp[row*4+3];
        t[c_l][n_l] = s / d;
    }
    __syncthreads();
    #pragma unroll
    for (int e = 0; e < 16; e++) {
        int idx = e * 256 + tid;
        int n_l = idx >> 6, c_l = idx & 63;
        attnT[(size_t)(nb + n_l) * 256 + cb + c_l] = f2bf(t[c_l][n_l]);
    }
}

extern "C" void kernel_launch(void* const* d_in, const int* in_sizes, int n_in,
                              void* d_out, int out_size, void* d_ws, size_t ws_size,
                              hipStream_t stream) {
    const float* x      = (const float*)d_in[0];
    const float* source = (const float*)d_in[1];
    const void*  mask   = d_in[3];
    const float* Wq = (const float*)d_in[4];  const float* bq = (const float*)d_in[5];
    const float* Wk = (const float*)d_in[6];  const float* bk = (const float*)d_in[7];
    const float* Wv = (const float*)d_in[8];  const float* bv = (const float*)d_in[9];
    const float* Wm = (const float*)d_in[10]; const float* bm = (const float*)d_in[11];
    const float* W1 = (const float*)d_in[12]; const float* b1 = (const float*)d_in[13];
    const float* W2 = (const float*)d_in[14]; const float* b2 = (const float*)d_in[15];

    float* y    = (float*)d_out;                // [256,4096]
    float* wout = y + (size_t)Dm * Nn;          // [4096,4096]

    char* ws = (char*)d_ws;
    int*      flag  = (int*)(ws + OFF_FLAG);
    float*    sminp = (float*)(ws + OFF_SMIN);
    float*    part  = (float*)(ws + OFF_PART);
    unsigned* kmax  = (unsigned*)(ws + OFF_KMAX);
    float*    mtarr = (float*)(ws + OFF_MT);
    float*    denp  = (float*)(ws + OFF_DENP);
    unsigned short* wb    = (unsigned short*)(ws + OFF_WB);
    unsigned char*  bits  = (unsigned char*)(ws + OFF_BITS);
    unsigned short* qb    = (unsigned short*)(ws + OFF_QB);
    unsigned short* kb    = (unsigned short*)(ws + OFF_KB);
    unsigned short* vb    = (unsigned short*)(ws + OFF_VB);
    unsigned short* hcat  = (unsigned short*)(ws + OFF_HCAT);
    unsigned short* attnT = (unsigned short*)(ws + OFF_ATTNT);
    unsigned short* xt    = (unsigned short*)(ws + OFF_XT);
    unsigned short* st    = (unsigned short*)(ws + OFF_ST);
    unsigned short* opart = (unsigned short*)(ws + OFF_OPART);
    unsigned short* h1t   = (unsigned short*)(ws + OFF_H1T);

    k_detect<<<1, 256, 0, stream>>>((const unsigned char*)mask, flag);
    k_maskbits<<<8192, 256, 0, stream>>>(mask, flag, bits);

    k_prep<<<dim3(128, 4), 256, 0, stream>>>(x, xt, hcat);
    k_prep<<<dim3(128, 4), 256, 0, stream>>>(source, st, nullptr);
    k_wcast<<<2560, 256, 0, stream>>>(Wq, Wk, Wv, Wm, W1, W2, wb);

    k_qkv<<<dim3(64, 4, 3), 256, 0, stream>>>(wb, bq, bk, bv, xt, st, qb, kb, vb);

    k_init<<<1, 64, 0, stream>>>(kmax);
    k_knorm<<<dim3(16, 4), 256, 0, stream>>>(kb, kmax);
    k_qnorm<<<64, 256, 0, stream>>>(qb, kmax, mtarr);

    k_min<<<dim3(32, 8), 512, 0, stream>>>(qb, kb, part);
    k_minreduce<<<1, 256, 0, stream>>>(part, sminp);

    k_wout<<<dim3(32, 8), 512, 0, stream>>>(qb, kb, (const unsigned long long*)bits, sminp, wout);

    k_pv<<<dim3(16, 16), 512, 0, stream>>>(qb, kb, vb, (const unsigned long long*)bits,
                                           sminp, mtarr, denp, opart);
    k_finish<<<dim3(64, 4), 256, 0, stream>>>(opart, denp, attnT);

    k_mgemm<256><<<dim3(64, 4), 256, 0, stream>>>(wb + WOFF_M, bm, attnT, hcat, 3);
    k_mgemm<512><<<dim3(64, 8), 256, 0, stream>>>(wb + WOFF_1, b1, hcat, h1t, 4);
    k_mgemm<512><<<dim3(64, 4), 256, 0, stream>>>(wb + WOFF_2, b2, h1t, y, 0);
}

// Round 7
// 198.123 us; speedup vs baseline: 7.5989x; 1.0505x over previous
//
#include <hip/hip_runtime.h>
#include <hip/hip_bf16.h>
#include <math.h>

#define Dm 256
#define Hh 4
#define Nn 4096
#define Mq 4096

typedef __attribute__((ext_vector_type(8))) short bf16x8;
typedef __attribute__((ext_vector_type(4))) float f32x4;
typedef _Float16 __attribute__((ext_vector_type(4))) f16x4;
typedef __fp16 __attribute__((ext_vector_type(2))) h16x2;

#define MFMA_BF16(a,b,c) __builtin_amdgcn_mfma_f32_16x16x32_bf16(a,b,c,0,0,0)
#define MFMA_F16x16(a,b,c) __builtin_amdgcn_mfma_f32_16x16x16f16(a,b,c,0,0,0)

#define MB (1u<<20)
// ---- workspace layout (bytes); 32MB proven ----
#define OFF_FLAG  0
#define OFF_SMIN  64
#define OFF_PART  1024                // 512 f32 -> ends 3072
#define OFF_KMAX  3072                // 4 u32
#define OFF_MT    4096                // 16384 f32 (64KB)
#define OFF_DENP  (128u<<10)          // 16384*4 f32 (256KB)
#define OFF_WB    (3u*MB/2)           // 655360 bf16 (1.25MB)
#define OFF_BITS  (3u*MB)             // 2MB bitmask
#define OFF_QB    (5u*MB)             // bf16 [h][n][64] 2MB
#define OFF_KB    (7u*MB)             // bf16 [h][m][64] swizzled 2MB
#define OFF_VB    (9u*MB)             // fp16 [h][dd][m] 2MB
#define OFF_HCAT  (11u*MB)            // bf16 [n][512] 4MB
#define OFF_ATTNT (15u*MB)            // bf16 [n][256] 2MB
// overlap region (xt/st die after QKV; opart dies before h1t written)
#define OFF_XT    (17u*MB)            // bf16 [n][256] 2MB
#define OFF_ST    (19u*MB)            // bf16 [n][256] 2MB
#define OFF_OPART (17u*MB)            // bf16 [4][c][n] 8MB -> ends 25MB
#define OFF_H1T   (17u*MB)            // bf16 [n][512] 4MB

#define WOFF_Q  0
#define WOFF_K  65536
#define WOFF_V  131072
#define WOFF_M  196608
#define WOFF_1  262144
#define WOFF_2  524288

__device__ __forceinline__ unsigned short f2bf(float x) {
    unsigned u = __float_as_uint(x);
    u += 0x7FFF + ((u >> 16) & 1);
    return (unsigned short)(u >> 16);
}
__device__ __forceinline__ float bf2f(unsigned short b) {
    return __uint_as_float(((unsigned)b) << 16);
}

// ---------------- mask dtype detection (+kmax zero) ----------------
__global__ void k_detect(const unsigned char* __restrict__ mb, int* __restrict__ flag,
                         unsigned* __restrict__ kmax) {
    __shared__ int c[5];
    if (threadIdx.x < 5) c[threadIdx.x] = 0;
    if (threadIdx.x < 4) kmax[threadIdx.x] = 0u;
    __syncthreads();
    for (int i = threadIdx.x; i < 16384; i += blockDim.x) {
        unsigned char b = mb[i];
        if (b) {
            atomicAdd(&c[i & 3], 1);
            if ((i & 7) == 4) atomicAdd(&c[4], 1);
        }
    }
    __syncthreads();
    if (threadIdx.x == 0) {
        int f;
        if (c[3] > 0 && c[0] == 0)          f = 3;
        else if (c[1] | c[2] | c[3])        f = 1;
        else if (c[4] > 0)                  f = 0;
        else                                f = 2;
        *flag = f;
    }
}

// ---------------- mask -> bitmask ----------------
__global__ void k_maskbits(const void* __restrict__ mp, const int* __restrict__ flagp,
                           unsigned char* __restrict__ bits) {
    size_t i = (size_t)blockIdx.x * 256 + threadIdx.x;
    const int flag = *flagp;
    size_t base = i * 8;
    unsigned b = 0;
    if (flag == 1) {
        unsigned long long u = *(const unsigned long long*)((const unsigned char*)mp + base);
        #pragma unroll
        for (int j = 0; j < 8; j++) b |= (unsigned)(((u >> (8*j)) & 0xFFull) != 0ull) << j;
    } else if (flag == 0) {
        const int* p = (const int*)mp;
        #pragma unroll
        for (int j = 0; j < 8; j++) b |= (unsigned)(p[base + j] != 0) << j;
    } else if (flag == 3) {
        const float* p = (const float*)mp;
        #pragma unroll
        for (int j = 0; j < 8; j++) b |= (unsigned)(p[base + j] != 0.0f) << j;
    } else {
        const unsigned long long* p = (const unsigned long long*)mp;
        #pragma unroll
        for (int j = 0; j < 8; j++) b |= (unsigned)(p[base + j] != 0ull) << j;
    }
    bits[i] = (unsigned char)b;
}

// ---------------- transpose-cast f32 [c][n] -> bf16 [n][c]; z=0: x (+hcat), z=1: source ----------------
__global__ __launch_bounds__(256) void k_prep(const float* __restrict__ x,
                                              const float* __restrict__ source,
                                              unsigned short* __restrict__ xt,
                                              unsigned short* __restrict__ st,
                                              unsigned short* __restrict__ hcat) {
    const int z = blockIdx.z;
    const float* src = z ? source : x;
    unsigned short* dst = z ? st : xt;
    unsigned short* dst2 = z ? nullptr : hcat;
    const int l = threadIdx.x & 63, g = threadIdx.x >> 6;
    const int c = blockIdx.y * 64 + l;
    const int n0 = blockIdx.x * 32 + g * 8;
    float4 v0 = *(const float4*)(src + (size_t)c * Nn + n0);
    float4 v1 = *(const float4*)(src + (size_t)c * Nn + n0 + 4);
    float vv[8] = {v0.x, v0.y, v0.z, v0.w, v1.x, v1.y, v1.z, v1.w};
    #pragma unroll
    for (int j = 0; j < 8; j++) {
        unsigned short b = f2bf(vv[j]);
        dst[(size_t)(n0 + j) * 256 + c] = b;
        if (dst2) dst2[(size_t)(n0 + j) * 512 + c] = b;
    }
}

// ---------------- cast all weights to bf16 ----------------
__global__ void k_wcast(const float* __restrict__ Wq, const float* __restrict__ Wk,
                        const float* __restrict__ Wv, const float* __restrict__ Wm,
                        const float* __restrict__ W1, const float* __restrict__ W2,
                        unsigned short* __restrict__ wb) {
    size_t i = (size_t)blockIdx.x * 256 + threadIdx.x;
    const float* s; size_t off;
    if      (i < 65536)               { s = Wq; off = i; }
    else if (i < 131072)              { s = Wk; off = i - 65536; }
    else if (i < 196608)              { s = Wv; off = i - 131072; }
    else if (i < 262144)              { s = Wm; off = i - 196608; }
    else if (i < 524288)              { s = W1; off = i - 262144; }
    else                              { s = W2; off = i - 524288; }
    wb[i] = f2bf(s[off]);
}

// ---------------- MFMA GEMM body ----------------
// modes: 0 f32 [o][n] (y); 1 bf16 qk-layout [h][n][dd] (qb); 2 fp16 v-layout [h][dd][m] (vb);
//        3 hcat[n][512] at c+256; 4 relu bf16 [n][512]; 5 kb swizzled [h][m][ddswz]
template<int KK>
__device__ __forceinline__ void gemm_body(const unsigned short* __restrict__ wb,
                                          const float* __restrict__ bias,
                                          const unsigned short* __restrict__ xt,
                                          void* __restrict__ out, int mode,
                                          int bx, int by) {
    const int tid = threadIdx.x, w = tid >> 6, lane = tid & 63;
    const int lg = lane >> 4, lr = lane & 15;
    const int o_base = by * 64 + w * 16;
    const int n_base = bx * 64;
    f32x4 acc[4];
    #pragma unroll
    for (int j = 0; j < 4; j++) acc[j] = (f32x4){0.f, 0.f, 0.f, 0.f};
    const unsigned short* wrow = wb + (size_t)(o_base + lr) * KK + lg * 8;
    const unsigned short* xrow = xt + (size_t)(n_base + lr) * KK + lg * 8;
    #pragma unroll
    for (int k0 = 0; k0 < KK; k0 += 32) {
        bf16x8 af = *(const bf16x8*)(wrow + k0);
        #pragma unroll
        for (int j = 0; j < 4; j++) {
            bf16x8 bfr = *(const bf16x8*)(xrow + (size_t)j * 16 * KK + k0);
            acc[j] = MFMA_BF16(af, bfr, acc[j]);
        }
    }
    float bv[4];
    #pragma unroll
    for (int r = 0; r < 4; r++) bv[r] = bias[o_base + lg * 4 + r];
    #pragma unroll
    for (int j = 0; j < 4; j++) {
        #pragma unroll
        for (int r = 0; r < 4; r++) {
            int o = o_base + lg * 4 + r;
            int n = n_base + j * 16 + lr;
            float v = acc[j][r] + bv[r];
            if (mode == 0) {
                ((float*)out)[(size_t)o * Nn + n] = v;
            } else if (mode == 1) {
                ((unsigned short*)out)[(((size_t)(o & 3)) * Nn + n) * 64 + (o >> 2)] = f2bf(v);
            } else if (mode == 2) {
                union { _Float16 h; unsigned short u; } cv; cv.h = (_Float16)v;
                ((unsigned short*)out)[(((size_t)(o & 3)) * 64 + (o >> 2)) * Mq + n] = cv.u;
            } else if (mode == 3) {
                ((unsigned short*)out)[(size_t)n * 512 + 256 + o] = f2bf(v);
            } else if (mode == 4) {
                ((unsigned short*)out)[(size_t)n * 512 + o] = f2bf(fmaxf(v, 0.f));
            } else {
                int dd = o >> 2, hh = o & 3, g = dd >> 3, pos = dd & 7;
                int slot = g ^ (n & 7);
                ((unsigned short*)out)[(((size_t)hh * Mq + n)) * 64 + slot * 8 + pos] = f2bf(v);
            }
        }
    }
}

template<int KK>
__global__ __launch_bounds__(256) void k_mgemm(const unsigned short* __restrict__ wb,
                                               const float* __restrict__ bias,
                                               const unsigned short* __restrict__ xt,
                                               void* __restrict__ out, int mode) {
    gemm_body<KK>(wb, bias, xt, out, mode, blockIdx.x, blockIdx.y);
}

__global__ __launch_bounds__(256) void k_qkv(const unsigned short* __restrict__ wb,
                                             const float* __restrict__ bq,
                                             const float* __restrict__ bk,
                                             const float* __restrict__ bv,
                                             const unsigned short* __restrict__ xt,
                                             const unsigned short* __restrict__ st,
                                             void* __restrict__ qb, void* __restrict__ kb,
                                             void* __restrict__ vb) {
    const int z = blockIdx.z;
    const float* bias = (z == 0) ? bq : ((z == 1) ? bk : bv);
    const unsigned short* X = (z == 0) ? xt : st;
    void* out = (z == 0) ? qb : ((z == 1) ? kb : vb);
    int mode = (z == 0) ? 1 : ((z == 1) ? 5 : 2);
    gemm_body<256>(wb + z * 65536, bias, X, out, mode, blockIdx.x, blockIdx.y);
}

// ---------------- norm-based row-max bound ----------------
__global__ __launch_bounds__(256) void k_knorm(const unsigned short* __restrict__ kb,
                                               unsigned* __restrict__ kmax) {
    const int h = blockIdx.y;
    const int m = blockIdx.x * 256 + threadIdx.x;
    const unsigned short* row = kb + ((size_t)(h * Mq + m) << 6);
    float s = 0.f;
    #pragma unroll
    for (int i = 0; i < 64; i++) { float v = bf2f(row[i]); s = fmaf(v, v, s); }
    __shared__ float red[256];
    red[threadIdx.x] = s;
    __syncthreads();
    for (int st = 128; st > 0; st >>= 1) {
        if (threadIdx.x < st) red[threadIdx.x] = fmaxf(red[threadIdx.x], red[threadIdx.x + st]);
        __syncthreads();
    }
    if (threadIdx.x == 0) atomicMax(kmax + h, __float_as_uint(red[0]));
}

__global__ __launch_bounds__(256) void k_qnorm(const unsigned short* __restrict__ qb,
                                               const unsigned* __restrict__ kmax,
                                               float* __restrict__ mtarr) {
    const int row = blockIdx.x * 256 + threadIdx.x;   // h*Nn + n
    const unsigned short* qr = qb + ((size_t)row << 6);
    float s = 0.f;
    #pragma unroll
    for (int i = 0; i < 64; i++) { float v = bf2f(qr[i]); s = fmaf(v, v, s); }
    float k2 = __uint_as_float(kmax[row >> 12]);
    mtarr[row] = sqrtf(s * k2) * 0.125f;   // |q|*|k|max/8 >= rowmax
}

// ---------------- global min of raw scores ----------------
// grid (32, 16), 512 threads; per wave n16 all heads; m256 per block, LDS-staged K.
__global__ __launch_bounds__(512) void k_min(
    const unsigned short* __restrict__ qb, const unsigned short* __restrict__ kb,
    float* __restrict__ partial) {
    __shared__ unsigned short kbuf[2][8192];   // [buf][h][m32][64] 32KB
    const int tid = threadIdx.x;
    const int w = tid >> 6, lane = tid & 63;
    const int lg = lane >> 4, lr = lane & 15;
    const int n0 = blockIdx.x * 128 + w * 16;
    const int m0 = blockIdx.y * 256;

    bf16x8 qf[4][2];
    #pragma unroll
    for (int h = 0; h < 4; h++)
        #pragma unroll
        for (int kh = 0; kh < 2; kh++)
            qf[h][kh] = *(const bf16x8*)(qb + (((size_t)h * Nn + n0 + lr) << 6) + kh*32 + lg*8);

    const int h0 = tid >> 8, q0 = tid & 255;
    const unsigned short* src0 = kb + (((size_t)h0 * Mq + m0) << 6) + q0 * 8;
    const unsigned short* src1 = kb + (((size_t)(h0 + 2) * Mq + m0) << 6) + q0 * 8;
    unsigned short* dst0 = &kbuf[0][h0 * 2048 + q0 * 8];
    unsigned short* dst1 = &kbuf[0][(h0 + 2) * 2048 + q0 * 8];

    float mn = INFINITY;

    bf16x8 r0 = *(const bf16x8*)(src0);
    bf16x8 r1 = *(const bf16x8*)(src1);
    *(bf16x8*)dst0 = r0;
    *(bf16x8*)dst1 = r1;
    __syncthreads();
    r0 = *(const bf16x8*)(src0 + 2048);
    r1 = *(const bf16x8*)(src1 + 2048);

    for (int t = 0; t < 8; t++) {
        const unsigned short* kB = &kbuf[t & 1][0];
        #pragma unroll
        for (int mi = 0; mi < 2; mi++) {
            const int rowoff = (mi * 16 + lr) * 64;
            #pragma unroll
            for (int h = 0; h < 4; h++) {
                bf16x8 a0 = *(const bf16x8*)(kB + h*2048 + rowoff + ((lg ^ (lr & 7)) << 3));
                bf16x8 a1 = *(const bf16x8*)(kB + h*2048 + rowoff + (((lg + 4) ^ (lr & 7)) << 3));
                f32x4 acc = (f32x4){0.f, 0.f, 0.f, 0.f};
                acc = MFMA_BF16(a0, qf[h][0], acc);
                acc = MFMA_BF16(a1, qf[h][1], acc);
                mn = fminf(mn, fminf(fminf(acc[0], acc[1]), fminf(acc[2], acc[3])));
            }
        }
        if (t < 7) {
            *(bf16x8*)(dst0 + (((t + 1) & 1) ? 8192 : 0)) = r0;
            *(bf16x8*)(dst1 + (((t + 1) & 1) ? 8192 : 0)) = r1;
        }
        __syncthreads();
        if (t < 6) {
            r0 = *(const bf16x8*)(src0 + (size_t)(t + 2) * 2048);
            r1 = *(const bf16x8*)(src1 + (size_t)(t + 2) * 2048);
        }
    }

    for (int off = 1; off < 64; off <<= 1) mn = fminf(mn, __shfl_xor(mn, off));
    __shared__ float wmin[8];
    if (lane == 0) wmin[w] = mn;
    __syncthreads();
    if (tid == 0) {
        float m2 = wmin[0];
        #pragma unroll
        for (int i = 1; i < 8; i++) m2 = fminf(m2, wmin[i]);
        partial[blockIdx.x * 16 + blockIdx.y] = m2 * 0.125f;
    }
}

__global__ void k_minreduce(const float* __restrict__ partial, float* __restrict__ smin) {
    const int tid = threadIdx.x;
    float mn = fminf(partial[tid], partial[tid + 256]);
    __shared__ float red[256];
    red[tid] = mn;
    __syncthreads();
    for (int st = 128; st > 0; st >>= 1) {
        if (tid < st) red[tid] = fminf(red[tid], red[tid + st]);
        __syncthreads();
    }
    if (tid == 0) *smin = red[0];
}

// ---------------- weights: full-K head-summed GEMM + mask epilogue ----------------
// grid (32, 16), 512 threads; m256 per block.
__global__ __launch_bounds__(512) void k_wout(
    const unsigned short* __restrict__ qb, const unsigned short* __restrict__ kb,
    const unsigned long long* __restrict__ bits,
    const float* __restrict__ sminp, float* __restrict__ wout) {
    __shared__ unsigned short kbuf[2][8192];
    const int tid = threadIdx.x;
    const int w = tid >> 6, lane = tid & 63;
    const int lg = lane >> 4, lr = lane & 15;
    const int n0 = blockIdx.x * 128 + w * 16;
    const int m0 = blockIdx.y * 256;
    const float smin = *sminp;

    bf16x8 qf[4][2];
    #pragma unroll
    for (int h = 0; h < 4; h++)
        #pragma unroll
        for (int kh = 0; kh < 2; kh++)
            qf[h][kh] = *(const bf16x8*)(qb + (((size_t)h * Nn + n0 + lr) << 6) + kh*32 + lg*8);

    const int h0 = tid >> 8, q0 = tid & 255;
    const unsigned short* src0 = kb + (((size_t)h0 * Mq + m0) << 6) + q0 * 8;
    const unsigned short* src1 = kb + (((size_t)(h0 + 2) * Mq + m0) << 6) + q0 * 8;
    unsigned short* dst0 = &kbuf[0][h0 * 2048 + q0 * 8];
    unsigned short* dst1 = &kbuf[0][(h0 + 2) * 2048 + q0 * 8];

    const unsigned long long* brow = bits + (((size_t)(n0 + lr)) << 6) + (m0 >> 6);
    unsigned long long bw = 0ull;

    bf16x8 r0 = *(const bf16x8*)(src0);
    bf16x8 r1 = *(const bf16x8*)(src1);
    *(bf16x8*)dst0 = r0;
    *(bf16x8*)dst1 = r1;
    __syncthreads();
    r0 = *(const bf16x8*)(src0 + 2048);
    r1 = *(const bf16x8*)(src1 + 2048);

    for (int t = 0; t < 8; t++) {
        const unsigned short* kB = &kbuf[t & 1][0];
        const int mch = m0 + t * 32;
        if ((t & 1) == 0) bw = brow[t >> 1];
        #pragma unroll
        for (int mi = 0; mi < 2; mi++) {
            const int rowoff = (mi * 16 + lr) * 64;
            f32x4 accA = (f32x4){0.f, 0.f, 0.f, 0.f};
            f32x4 accB = (f32x4){0.f, 0.f, 0.f, 0.f};
            #pragma unroll
            for (int h = 0; h < 2; h++) {
                bf16x8 a0 = *(const bf16x8*)(kB + h*2048 + rowoff + ((lg ^ (lr & 7)) << 3));
                bf16x8 a1 = *(const bf16x8*)(kB + h*2048 + rowoff + (((lg + 4) ^ (lr & 7)) << 3));
                accA = MFMA_BF16(a0, qf[h][0], accA);
                accA = MFMA_BF16(a1, qf[h][1], accA);
            }
            #pragma unroll
            for (int h = 2; h < 4; h++) {
                bf16x8 a0 = *(const bf16x8*)(kB + h*2048 + rowoff + ((lg ^ (lr & 7)) << 3));
                bf16x8 a1 = *(const bf16x8*)(kB + h*2048 + rowoff + (((lg + 4) ^ (lr & 7)) << 3));
                accB = MFMA_BF16(a0, qf[h][0], accB);
                accB = MFMA_BF16(a1, qf[h][1], accB);
            }
            const int shb = (t & 1) * 32 + mi * 16 + lg * 4;
            f32x4 wv;
            #pragma unroll
            for (int r = 0; r < 4; r++) {
                bool b = (bw >> (shb + r)) & 1ull;
                wv[r] = fmaf(accA[r] + accB[r], 0.03125f, b ? 0.f : smin);
            }
            *(f32x4*)(wout + (size_t)(n0 + lr) * Mq + mch + mi * 16 + lg * 4) = wv;
        }
        if (t < 7) {
            *(bf16x8*)(dst0 + (((t + 1) & 1) ? 8192 : 0)) = r0;
            *(bf16x8*)(dst1 + (((t + 1) & 1) ? 8192 : 0)) = r1;
        }
        __syncthreads();
        if (t < 6) {
            r0 = *(const bf16x8*)(src0 + (size_t)(t + 2) * 2048);
            r1 = *(const bf16x8*)(src1 + (size_t)(t + 2) * 2048);
        }
    }
}

// ---------------- flash PV: grid (32, 16=h4*mb4), 512 thr, 8 waves x n16, full dd ----------------
__global__ __launch_bounds__(512) void k_pv(
    const unsigned short* __restrict__ qb, const unsigned short* __restrict__ kb,
    const unsigned short* __restrict__ vbh,
    const unsigned long long* __restrict__ bits,
    const float* __restrict__ sminp, const float* __restrict__ mtarr,
    float* __restrict__ denp, unsigned short* __restrict__ opart) {
    __shared__ unsigned short kbuf[2][4096];   // [buf][m64][64] bf16 16KB
    __shared__ unsigned short vbuf[2][4096];   // [buf][(mi4 ds4)16 lr][slot4][4] f16 16KB
    const int tid = threadIdx.x;
    const int w = tid >> 6, lane = tid & 63;
    const int lg = lane >> 4, lr = lane & 15;
    const int h = blockIdx.y & 3, mb = blockIdx.y >> 2;
    const int n0 = blockIdx.x * 128 + w * 16;
    const int m0 = mb * 1024;
    const float smin = *sminp;
    const float sminc = fmaxf(smin, 0.f);

    bf16x8 qf0 = *(const bf16x8*)(qb + (((size_t)h * Nn + n0 + lr) << 6) + lg*8);
    bf16x8 qf1 = *(const bf16x8*)(qb + (((size_t)h * Nn + n0 + lr) << 6) + 32 + lg*8);
    float mtE = mtarr[(size_t)h * Nn + n0 + lr] + sminc;
    const float cT = -mtE * 1.44269504f;
    const float cF = cT + smin * 1.44269504f;

    f32x4 oacc[4];
    #pragma unroll
    for (int ds = 0; ds < 4; ds++) oacc[ds] = (f32x4){0.f, 0.f, 0.f, 0.f};
    float dsum = 0.f;

    // K staging: 16B linear per thread; V staging: swizzled slots
    const unsigned short* ksrc = kb + (((size_t)h * Mq + m0) << 6) + tid * 8;
    const int vdd = tid >> 3, vj = tid & 7;
    const unsigned short* vsrc = vbh + (size_t)(h * 64 + vdd) * Mq + m0 + vj * 8;
    const int vds = vdd >> 4, vlr = vdd & 15, vmi = vj >> 1;
    const int vswz = (vlr >> 2) & 3;
    const int vbase = ((vmi * 4 + vds) * 16 + vlr) * 4;
    const int vdst0 = (vbase + (((vj & 1) * 2 + 0) ^ vswz)) * 4;
    const int vdst1 = (vbase + (((vj & 1) * 2 + 1) ^ vswz)) * 4;

    union { bf16x8 v; unsigned long long q[2]; } rv;
    bf16x8 rk = *(const bf16x8*)(ksrc);
    rv.v = *(const bf16x8*)(vsrc);
    *(bf16x8*)&kbuf[0][tid * 8] = rk;
    *(unsigned long long*)&vbuf[0][vdst0] = rv.q[0];
    *(unsigned long long*)&vbuf[0][vdst1] = rv.q[1];
    __syncthreads();
    rk = *(const bf16x8*)(ksrc + 4096);
    rv.v = *(const bf16x8*)(vsrc + 64);

    const unsigned long long* brow = bits + (((size_t)(n0 + lr)) << 6) + (m0 >> 6);
    const int kslot0 = (lg ^ (lr & 7)) << 3;
    const int kslot1 = ((lg + 4) ^ (lr & 7)) << 3;
    const int vrslot = (lg ^ ((lr >> 2) & 3)) * 4;

    for (int t = 0; t < 16; t++) {
        const unsigned short* kB = &kbuf[t & 1][0];
        const unsigned short* vB = &vbuf[t & 1][0];
        unsigned long long bw = brow[t];
        #pragma unroll
        for (int mi = 0; mi < 4; mi++) {
            const int rowoff = (mi * 16 + lr) * 64;
            bf16x8 a0 = *(const bf16x8*)(kB + rowoff + kslot0);
            bf16x8 a1 = *(const bf16x8*)(kB + rowoff + kslot1);
            f16x4 vf[4];
            #pragma unroll
            for (int ds = 0; ds < 4; ds++)
                vf[ds] = *(const f16x4*)&vB[((mi * 4 + ds) * 16 + lr) * 16 + vrslot];
            f32x4 acc = (f32x4){0.f, 0.f, 0.f, 0.f};
            acc = MFMA_BF16(a0, qf0, acc);
            acc = MFMA_BF16(a1, qf1, acc);
            const int shb = mi * 16 + lg * 4;
            float p0 = exp2f(fmaf(acc[0], 0.18033688f, ((bw >> (shb + 0)) & 1ull) ? cT : cF));
            float p1 = exp2f(fmaf(acc[1], 0.18033688f, ((bw >> (shb + 1)) & 1ull) ? cT : cF));
            float p2 = exp2f(fmaf(acc[2], 0.18033688f, ((bw >> (shb + 2)) & 1ull) ? cT : cF));
            float p3 = exp2f(fmaf(acc[3], 0.18033688f, ((bw >> (shb + 3)) & 1ull) ? cT : cF));
            dsum += (p0 + p1) + (p2 + p3);
            union { h16x2 h2[2]; f16x4 f4; } pu;
            pu.h2[0] = __builtin_amdgcn_cvt_pkrtz(p0, p1);
            pu.h2[1] = __builtin_amdgcn_cvt_pkrtz(p2, p3);
            f16x4 pf = pu.f4;
            #pragma unroll
            for (int ds = 0; ds < 4; ds++)
                oacc[ds] = MFMA_F16x16(pf, vf[ds], oacc[ds]);
        }
        if (t < 15) {
            *(bf16x8*)&kbuf[(t + 1) & 1][tid * 8] = rk;
            *(unsigned long long*)&vbuf[(t + 1) & 1][vdst0] = rv.q[0];
            *(unsigned long long*)&vbuf[(t + 1) & 1][vdst1] = rv.q[1];
        }
        __syncthreads();
        if (t < 14) {
            rk = *(const bf16x8*)(ksrc + (size_t)(t + 2) * 4096);
            rv.v = *(const bf16x8*)(vsrc + (size_t)(t + 2) * 64);
        }
    }

    dsum += __shfl_xor(dsum, 16);
    dsum += __shfl_xor(dsum, 32);
    if (lane < 16)
        denp[((size_t)h * Nn + n0 + lane) * 4 + mb] = dsum;

    unsigned short* op = opart + (size_t)mb * (Dm * Nn);
    #pragma unroll
    for (int ds = 0; ds < 4; ds++) {
        int c = (ds * 16 + lr) * 4 + h;
        int n = n0 + lg * 4;
        unsigned long long pk =
            (unsigned long long)f2bf(oacc[ds][0]) |
            ((unsigned long long)f2bf(oacc[ds][1]) << 16) |
            ((unsigned long long)f2bf(oacc[ds][2]) << 32) |
            ((unsigned long long)f2bf(oacc[ds][3]) << 48);
        *(unsigned long long*)&op[(size_t)c * Nn + n] = pk;
    }
}

// ---------------- finish: sum partials, normalize, transpose -> attnT[n][c] bf16 ----------------
__global__ __launch_bounds__(256) void k_finish(const unsigned short* __restrict__ opart,
                                                const float* __restrict__ denp,
                                                unsigned short* __restrict__ attnT) {
    __shared__ float t[64][65];
    const int cb = blockIdx.y * 64, nb = blockIdx.x * 64;
    const int tid = threadIdx.x;
    #pragma unroll
    for (int e = 0; e < 16; e++) {
        int idx = e * 256 + tid;
        int c_l = idx >> 6, n_l = idx & 63;
        int c = cb + c_l, n = nb + n_l;
        float s = 0.f;
        #pragma unroll
        for (int y = 0; y < 4; y++)
            s += bf2f(opart[(size_t)y * (Dm*Nn) + (size_t)c * Nn + n]);
        size_t row = (size_t)(c & 3) * Nn + n;
        float d = denp[row*4] + denp[row*4+1] + denp[row*4+2] + denp[row*4+3];
        t[c_l][n_l] = s / d;
    }
    __syncthreads();
    #pragma unroll
    for (int e = 0; e < 16; e++) {
        int idx = e * 256 + tid;
        int n_l = idx >> 6, c_l = idx & 63;
        attnT[(size_t)(nb + n_l) * 256 + cb + c_l] = f2bf(t[c_l][n_l]);
    }
}

extern "C" void kernel_launch(void* const* d_in, const int* in_sizes, int n_in,
                              void* d_out, int out_size, void* d_ws, size_t ws_size,
                              hipStream_t stream) {
    const float* x      = (const float*)d_in[0];
    const float* source = (const float*)d_in[1];
    const void*  mask   = d_in[3];
    const float* Wq = (const float*)d_in[4];  const float* bq = (const float*)d_in[5];
    const float* Wk = (const float*)d_in[6];  const float* bk = (const float*)d_in[7];
    const float* Wv = (const float*)d_in[8];  const float* bv = (const float*)d_in[9];
    const float* Wm = (const float*)d_in[10]; const float* bm = (const float*)d_in[11];
    const float* W1 = (const float*)d_in[12]; const float* b1 = (const float*)d_in[13];
    const float* W2 = (const float*)d_in[14]; const float* b2 = (const float*)d_in[15];

    float* y    = (float*)d_out;                // [256,4096]
    float* wout = y + (size_t)Dm * Nn;          // [4096,4096]

    char* ws = (char*)d_ws;
    int*      flag  = (int*)(ws + OFF_FLAG);
    float*    sminp = (float*)(ws + OFF_SMIN);
    float*    part  = (float*)(ws + OFF_PART);
    unsigned* kmax  = (unsigned*)(ws + OFF_KMAX);
    float*    mtarr = (float*)(ws + OFF_MT);
    float*    denp  = (float*)(ws + OFF_DENP);
    unsigned short* wb    = (unsigned short*)(ws + OFF_WB);
    unsigned char*  bits  = (unsigned char*)(ws + OFF_BITS);
    unsigned short* qb    = (unsigned short*)(ws + OFF_QB);
    unsigned short* kb    = (unsigned short*)(ws + OFF_KB);
    unsigned short* vb    = (unsigned short*)(ws + OFF_VB);
    unsigned short* hcat  = (unsigned short*)(ws + OFF_HCAT);
    unsigned short* attnT = (unsigned short*)(ws + OFF_ATTNT);
    unsigned short* xt    = (unsigned short*)(ws + OFF_XT);
    unsigned short* st    = (unsigned short*)(ws + OFF_ST);
    unsigned short* opart = (unsigned short*)(ws + OFF_OPART);
    unsigned short* h1t   = (unsigned short*)(ws + OFF_H1T);

    k_detect<<<1, 256, 0, stream>>>((const unsigned char*)mask, flag, kmax);
    k_maskbits<<<8192, 256, 0, stream>>>(mask, flag, bits);

    k_prep<<<dim3(128, 4, 2), 256, 0, stream>>>(x, source, xt, st, hcat);
    k_wcast<<<2560, 256, 0, stream>>>(Wq, Wk, Wv, Wm, W1, W2, wb);

    k_qkv<<<dim3(64, 4, 3), 256, 0, stream>>>(wb, bq, bk, bv, xt, st, qb, kb, vb);

    k_knorm<<<dim3(16, 4), 256, 0, stream>>>(kb, kmax);
    k_qnorm<<<64, 256, 0, stream>>>(qb, kmax, mtarr);

    k_min<<<dim3(32, 16), 512, 0, stream>>>(qb, kb, part);
    k_minreduce<<<1, 256, 0, stream>>>(part, sminp);

    k_wout<<<dim3(32, 16), 512, 0, stream>>>(qb, kb, (const unsigned long long*)bits, sminp, wout);

    k_pv<<<dim3(32, 16), 512, 0, stream>>>(qb, kb, vb, (const unsigned long long*)bits,
                                           sminp, mtarr, denp, opart);
    k_finish<<<dim3(64, 4), 256, 0, stream>>>(opart, denp, attnT);

    k_mgemm<256><<<dim3(64, 4), 256, 0, stream>>>(wb + WOFF_M, bm, attnT, hcat, 3);
    k_mgemm<512><<<dim3(64, 8), 256, 0, stream>>>(wb + WOFF_1, b1, hcat, h1t, 4);
    k_mgemm<512><<<dim3(64, 4), 256, 0, stream>>>(wb + WOFF_2, b2, h1t, y, 0);
}